// Round 1
// baseline (1222.253 us; speedup 1.0000x reference)
//
#include <hip/hip_runtime.h>

#define N_NODES 50000
#define N_EDGES 800000
#define D_IN 96
#define HID 128

// ---------------------------------------------------------------------------
// CSR build: count in-degree, exclusive scan (single block), fill edge ids.
// ---------------------------------------------------------------------------
__global__ void count_kernel(const int* __restrict__ dst, int* __restrict__ cnt, int E) {
    int e = blockIdx.x * 256 + threadIdx.x;
    if (e < E) atomicAdd(&cnt[dst[e]], 1);
}

__global__ __launch_bounds__(1024) void scan_kernel(const int* __restrict__ cnt,
                                                    int* __restrict__ csr_ptr,
                                                    int* __restrict__ cursor,
                                                    float* __restrict__ dinv,
                                                    int N) {
    // N = 50000, 1024 threads, 49 elements per thread (49*1024 = 50176 >= N)
    __shared__ int part[1024];
    const int CH = 49;
    int t = threadIdx.x;
    int start = t * CH;
    int end = min(start + CH, N);
    int s = 0;
    for (int i = start; i < end; i++) s += cnt[i];
    part[t] = s;
    __syncthreads();
    // Hillis-Steele inclusive scan over the 1024 partials
    for (int off = 1; off < 1024; off <<= 1) {
        int v = (t >= off) ? part[t - off] : 0;
        __syncthreads();
        part[t] += v;
        __syncthreads();
    }
    int run = part[t] - s;  // exclusive base for this thread's chunk
    for (int i = start; i < end; i++) {
        csr_ptr[i] = run;
        cursor[i] = run;
        int c = cnt[i];
        // deg[i] = indeg + 1 (self loop); always > 0
        dinv[i] = 1.0f / sqrtf((float)(c + 1));
        run += c;
    }
    if (t == 1023) csr_ptr[N] = part[1023];
}

__global__ void fill_kernel(const int* __restrict__ src, const int* __restrict__ dst,
                            int* __restrict__ cursor, int* __restrict__ csr_src, int E) {
    int e = blockIdx.x * 256 + threadIdx.x;
    if (e < E) {
        int pos = atomicAdd(&cursor[dst[e]], 1);
        csr_src[pos] = src[e];
    }
}

// ---------------------------------------------------------------------------
// Node GEMM: out[M][128] = (in[M][K] @ W[K][128]) (+bias, +relu optional)
// 32 rows per block, 256 threads: col = tid&127, rowgroup = tid>>7 (16 rows each)
// ---------------------------------------------------------------------------
__global__ __launch_bounds__(256) void gemm_kernel(const float* __restrict__ in,
                                                   const float* __restrict__ W,
                                                   const float* __restrict__ bias,
                                                   float* __restrict__ out,
                                                   int M, int K, int dorelu) {
    __shared__ float xs[32 * 128];
    int tid = threadIdx.x;
    int M0 = blockIdx.x * 32;
    int K4 = K >> 2;
    // Stage 32 x K input tile (float4, zero-padded past M)
    for (int i = tid; i < 32 * K4; i += 256) {
        int r = i / K4, c4 = i - r * K4;
        float4 v = make_float4(0.f, 0.f, 0.f, 0.f);
        if (M0 + r < M) v = *(const float4*)&in[(size_t)(M0 + r) * K + c4 * 4];
        *(float4*)&xs[r * K + c4 * 4] = v;
    }
    __syncthreads();
    int col = tid & 127, rg = tid >> 7;
    float acc[16];
#pragma unroll
    for (int r = 0; r < 16; r++) acc[r] = 0.f;
    const float* xb = &xs[rg * 16 * K];
    for (int k4 = 0; k4 < K4; k4++) {
        float w0 = W[(k4 * 4 + 0) * 128 + col];
        float w1 = W[(k4 * 4 + 1) * 128 + col];
        float w2 = W[(k4 * 4 + 2) * 128 + col];
        float w3 = W[(k4 * 4 + 3) * 128 + col];
#pragma unroll
        for (int r = 0; r < 16; r++) {
            float4 a = *(const float4*)&xb[r * K + k4 * 4];
            acc[r] = fmaf(a.x, w0, acc[r]);
            acc[r] = fmaf(a.y, w1, acc[r]);
            acc[r] = fmaf(a.z, w2, acc[r]);
            acc[r] = fmaf(a.w, w3, acc[r]);
        }
    }
    float bv = bias ? bias[col] : 0.f;
#pragma unroll
    for (int r = 0; r < 16; r++) {
        int row = M0 + rg * 16 + r;
        if (row < M) {
            float v = acc[r] + bv;
            if (dorelu) v = fmaxf(v, 0.f);
            out[(size_t)row * 128 + col] = v;
        }
    }
}

// ---------------------------------------------------------------------------
// GCN aggregation: out[i] = relu( sum_{e: dst=i} xw[src_e]*dinv[src]*dinv[i]
//                                 + xw[i]*dinv[i]^2 + b )
// One block per node, 128 threads (one per feature).
// ---------------------------------------------------------------------------
__global__ void aggregate_kernel(const float* __restrict__ xw,
                                 const float* __restrict__ dinv,
                                 const int* __restrict__ ptr,
                                 const int* __restrict__ csrc,
                                 const float* __restrict__ bias,
                                 float* __restrict__ out) {
    int i = blockIdx.x;
    int c = threadIdx.x;
    float di = dinv[i];
    float acc = xw[(size_t)i * 128 + c] * di * di;
    int s0 = ptr[i], s1 = ptr[i + 1];
    for (int j = s0; j < s1; j++) {
        int s = csrc[j];
        acc += xw[(size_t)s * 128 + c] * (dinv[s] * di);
    }
    out[(size_t)i * 128 + c] = fmaxf(acc + bias[c], 0.f);
}

// ---------------------------------------------------------------------------
// Edge MLP: ef = [h2[src], h2[dst]] (256), hid = relu(ef@Wm1+bm1) (128),
// logit = hid@Wm2 + bm2. 64 edges per block, 256 threads, 4x8 reg blocking.
// hid is never materialized to global memory.
// ---------------------------------------------------------------------------
__global__ __launch_bounds__(256) void edge_mlp_kernel(const float* __restrict__ h2,
                                                       const int* __restrict__ src,
                                                       const int* __restrict__ dst,
                                                       const float* __restrict__ Wm1,
                                                       const float* __restrict__ bm1,
                                                       const float* __restrict__ Wm2,
                                                       const float* __restrict__ bm2,
                                                       float* __restrict__ out, int E) {
    __shared__ float efs[64 * 16];    // EF k-slice: 64 edges x 16 k
    __shared__ float wts[16 * 128];   // Wm1 k-slice: 16 k x 128 cols
    __shared__ float red[64 * 17];    // logit reduction (padded)
    int tid = threadIdx.x;
    int e0 = blockIdx.x * 64;
    int tx = tid & 15;   // col group: cols tx*8 .. tx*8+7
    int ty = tid >> 4;   // row group: rows ty*4 .. ty*4+3
    float acc[4][8];
#pragma unroll
    for (int r = 0; r < 4; r++)
#pragma unroll
        for (int j = 0; j < 8; j++) acc[r][j] = 0.f;

    // staging mapping for efs: row = tid>>2 (0..63), k quad = tid&3
    int sr = tid >> 2, sk = tid & 3;
    int me = e0 + sr;
    bool rowok = me < E;
    int nsrc = 0, ndst = 0;
    if (rowok) { nsrc = src[me]; ndst = dst[me]; }

    for (int k0 = 0; k0 < 256; k0 += 16) {
        // stage EF slice: first 128 k's come from h2[src], rest from h2[dst]
        int node = (k0 < 128) ? nsrc : ndst;
        float4 v = make_float4(0.f, 0.f, 0.f, 0.f);
        if (rowok) v = *(const float4*)&h2[(size_t)node * 128 + (k0 & 127) + sk * 4];
        *(float4*)&efs[sr * 16 + sk * 4] = v;
        // stage Wm1 slice: row = ty (0..15), cols tx*8..+8
        const float4* wp = (const float4*)&Wm1[(size_t)(k0 + ty) * 128 + tx * 8];
        float4 w0 = wp[0], w1 = wp[1];
        *(float4*)&wts[ty * 128 + tx * 8] = w0;
        *(float4*)&wts[ty * 128 + tx * 8 + 4] = w1;
        __syncthreads();
#pragma unroll
        for (int kk = 0; kk < 16; kk++) {
            float4 b0 = *(const float4*)&wts[kk * 128 + tx * 8];
            float4 b1 = *(const float4*)&wts[kk * 128 + tx * 8 + 4];
            float bb[8] = {b0.x, b0.y, b0.z, b0.w, b1.x, b1.y, b1.z, b1.w};
#pragma unroll
            for (int r = 0; r < 4; r++) {
                float a = efs[(ty * 4 + r) * 16 + kk];
#pragma unroll
                for (int j = 0; j < 8; j++) acc[r][j] = fmaf(a, bb[j], acc[r][j]);
            }
        }
        __syncthreads();
    }

    // epilogue: relu(acc + bm1) dot Wm2, reduce across the 16 col-groups
#pragma unroll
    for (int r = 0; r < 4; r++) {
        float pr = 0.f;
#pragma unroll
        for (int j = 0; j < 8; j++) {
            float h = acc[r][j] + bm1[tx * 8 + j];
            h = fmaxf(h, 0.f);
            pr = fmaf(h, Wm2[tx * 8 + j], pr);
        }
        red[(ty * 4 + r) * 17 + tx] = pr;
    }
    __syncthreads();
    if (tid < 64) {
        float s = bm2[0];
#pragma unroll
        for (int i = 0; i < 16; i++) s += red[tid * 17 + i];
        if (e0 + tid < E) out[e0 + tid] = s;
    }
}

// ---------------------------------------------------------------------------
extern "C" void kernel_launch(void* const* d_in, const int* in_sizes, int n_in,
                              void* d_out, int out_size, void* d_ws, size_t ws_size,
                              hipStream_t stream) {
    const float* x    = (const float*)d_in[0];
    const int* eidx   = (const int*)d_in[1];
    const float* W_in = (const float*)d_in[2];
    const float* b_in = (const float*)d_in[3];
    const float* W1   = (const float*)d_in[4];
    const float* b1   = (const float*)d_in[5];
    const float* W2   = (const float*)d_in[6];
    const float* b2   = (const float*)d_in[7];
    const float* Wm1  = (const float*)d_in[8];
    const float* bm1  = (const float*)d_in[9];
    const float* Wm2  = (const float*)d_in[10];
    const float* bm2  = (const float*)d_in[11];
    float* out = (float*)d_out;
    const int* src = eidx;
    const int* dst = eidx + N_EDGES;

    // workspace bump allocator (256B aligned)
    char* w = (char*)d_ws;
    size_t off = 0;
    auto alloc = [&](size_t bytes) -> char* {
        char* p = w + off;
        off = (off + bytes + 255) & ~(size_t)255;
        return p;
    };
    int* cnt      = (int*)alloc((size_t)N_NODES * 4);
    int* csr_ptr  = (int*)alloc((size_t)(N_NODES + 1) * 4);
    int* cursor   = (int*)alloc((size_t)N_NODES * 4);
    float* dinv   = (float*)alloc((size_t)N_NODES * 4);
    int* csr_src  = (int*)alloc((size_t)N_EDGES * 4);
    float* bufA   = (float*)alloc((size_t)N_NODES * HID * 4);
    float* bufB   = (float*)alloc((size_t)N_NODES * HID * 4);

    hipMemsetAsync(cnt, 0, (size_t)N_NODES * 4, stream);
    count_kernel<<<(N_EDGES + 255) / 256, 256, 0, stream>>>(dst, cnt, N_EDGES);
    scan_kernel<<<1, 1024, 0, stream>>>(cnt, csr_ptr, cursor, dinv, N_NODES);
    fill_kernel<<<(N_EDGES + 255) / 256, 256, 0, stream>>>(src, dst, cursor, csr_src, N_EDGES);

    // h0 = relu(x @ W_in + b_in)                -> bufA
    gemm_kernel<<<(N_NODES + 31) / 32, 256, 0, stream>>>(x, W_in, b_in, bufA, N_NODES, D_IN, 1);
    // xw1 = h0 @ W1                             -> bufB
    gemm_kernel<<<(N_NODES + 31) / 32, 256, 0, stream>>>(bufA, W1, nullptr, bufB, N_NODES, HID, 0);
    // h1 = relu(aggregate(xw1) + b1)            -> bufA
    aggregate_kernel<<<N_NODES, 128, 0, stream>>>(bufB, dinv, csr_ptr, csr_src, b1, bufA);
    // xw2 = h1 @ W2                             -> bufB
    gemm_kernel<<<(N_NODES + 31) / 32, 256, 0, stream>>>(bufA, W2, nullptr, bufB, N_NODES, HID, 0);
    // h2 = relu(aggregate(xw2) + b2)            -> bufA
    aggregate_kernel<<<N_NODES, 128, 0, stream>>>(bufB, dinv, csr_ptr, csr_src, b2, bufA);
    // logits                                    -> out
    edge_mlp_kernel<<<(N_EDGES + 63) / 64, 256, 0, stream>>>(bufA, src, dst, Wm1, bm1, Wm2, bm2, out, N_EDGES);
}

// Round 2
// 827.336 us; speedup vs baseline: 1.4773x; 1.4773x over previous
//
#include <hip/hip_runtime.h>

#define N_NODES 50000
#define N_EDGES 800000
#define D_IN 96
#define HID 128

typedef __attribute__((ext_vector_type(8))) __bf16 bf16x8;
typedef __attribute__((ext_vector_type(16))) float f32x16;

// ---------------------------------------------------------------------------
// CSR build: count in-degree, exclusive scan (single block), fill edge ids.
// ---------------------------------------------------------------------------
__global__ void count_kernel(const int* __restrict__ dst, int* __restrict__ cnt, int E) {
    int e = blockIdx.x * 256 + threadIdx.x;
    if (e < E) atomicAdd(&cnt[dst[e]], 1);
}

__global__ __launch_bounds__(1024) void scan_kernel(const int* __restrict__ cnt,
                                                    int* __restrict__ csr_ptr,
                                                    int* __restrict__ cursor,
                                                    float* __restrict__ dinv,
                                                    int N) {
    __shared__ int part[1024];
    const int CH = 49;
    int t = threadIdx.x;
    int start = t * CH;
    int end = min(start + CH, N);
    int s = 0;
    for (int i = start; i < end; i++) s += cnt[i];
    part[t] = s;
    __syncthreads();
    for (int off = 1; off < 1024; off <<= 1) {
        int v = (t >= off) ? part[t - off] : 0;
        __syncthreads();
        part[t] += v;
        __syncthreads();
    }
    int run = part[t] - s;
    for (int i = start; i < end; i++) {
        csr_ptr[i] = run;
        cursor[i] = run;
        int c = cnt[i];
        dinv[i] = 1.0f / sqrtf((float)(c + 1));
        run += c;
    }
    if (t == 1023) csr_ptr[N] = part[1023];
}

__global__ void fill_kernel(const int* __restrict__ src, const int* __restrict__ dst,
                            int* __restrict__ cursor, int* __restrict__ csr_src, int E) {
    int e = blockIdx.x * 256 + threadIdx.x;
    if (e < E) {
        int pos = atomicAdd(&cursor[dst[e]], 1);
        csr_src[pos] = src[e];
    }
}

// ---------------------------------------------------------------------------
// Node GEMM: out[M][128] = (in[M][K] @ W[K][128]) (+bias, +relu optional)
// ---------------------------------------------------------------------------
__global__ __launch_bounds__(256) void gemm_kernel(const float* __restrict__ in,
                                                   const float* __restrict__ W,
                                                   const float* __restrict__ bias,
                                                   float* __restrict__ out,
                                                   int M, int K, int dorelu) {
    __shared__ float xs[32 * 128];
    int tid = threadIdx.x;
    int M0 = blockIdx.x * 32;
    int K4 = K >> 2;
    for (int i = tid; i < 32 * K4; i += 256) {
        int r = i / K4, c4 = i - r * K4;
        float4 v = make_float4(0.f, 0.f, 0.f, 0.f);
        if (M0 + r < M) v = *(const float4*)&in[(size_t)(M0 + r) * K + c4 * 4];
        *(float4*)&xs[r * K + c4 * 4] = v;
    }
    __syncthreads();
    int col = tid & 127, rg = tid >> 7;
    float acc[16];
#pragma unroll
    for (int r = 0; r < 16; r++) acc[r] = 0.f;
    const float* xb = &xs[rg * 16 * K];
    for (int k4 = 0; k4 < K4; k4++) {
        float w0 = W[(k4 * 4 + 0) * 128 + col];
        float w1 = W[(k4 * 4 + 1) * 128 + col];
        float w2 = W[(k4 * 4 + 2) * 128 + col];
        float w3 = W[(k4 * 4 + 3) * 128 + col];
#pragma unroll
        for (int r = 0; r < 16; r++) {
            float4 a = *(const float4*)&xb[r * K + k4 * 4];
            acc[r] = fmaf(a.x, w0, acc[r]);
            acc[r] = fmaf(a.y, w1, acc[r]);
            acc[r] = fmaf(a.z, w2, acc[r]);
            acc[r] = fmaf(a.w, w3, acc[r]);
        }
    }
    float bv = bias ? bias[col] : 0.f;
#pragma unroll
    for (int r = 0; r < 16; r++) {
        int row = M0 + rg * 16 + r;
        if (row < M) {
            float v = acc[r] + bv;
            if (dorelu) v = fmaxf(v, 0.f);
            out[(size_t)row * 128 + col] = v;
        }
    }
}

// ---------------------------------------------------------------------------
// GCN aggregation
// ---------------------------------------------------------------------------
__global__ void aggregate_kernel(const float* __restrict__ xw,
                                 const float* __restrict__ dinv,
                                 const int* __restrict__ ptr,
                                 const int* __restrict__ csrc,
                                 const float* __restrict__ bias,
                                 float* __restrict__ out) {
    int i = blockIdx.x;
    int c = threadIdx.x;
    float di = dinv[i];
    float acc = xw[(size_t)i * 128 + c] * di * di;
    int s0 = ptr[i], s1 = ptr[i + 1];
    for (int j = s0; j < s1; j++) {
        int s = csrc[j];
        acc += xw[(size_t)s * 128 + c] * (dinv[s] * di);
    }
    out[(size_t)i * 128 + c] = fmaxf(acc + bias[c], 0.f);
}

// ---------------------------------------------------------------------------
// Split fp32 -> (hi, lo) bf16 with RNE.
// ---------------------------------------------------------------------------
__device__ inline unsigned short f2bf(float f) {
    unsigned int u = __float_as_uint(f);
    return (unsigned short)((u + 0x7fffu + ((u >> 16) & 1u)) >> 16);
}

__global__ __launch_bounds__(256) void split_bf16_kernel(const float* __restrict__ in,
                                                         unsigned short* __restrict__ hi,
                                                         unsigned short* __restrict__ lo,
                                                         int n) {
    int i = blockIdx.x * 256 + threadIdx.x;
    if (i < n) {
        float f = in[i];
        unsigned short h = f2bf(f);
        hi[i] = h;
        float fh = __uint_as_float((unsigned int)h << 16);
        lo[i] = f2bf(f - fh);
    }
}

// Pack Wm1 [256x128] fp32 into B-fragment order (hi/lo bf16):
// idx = ((wc*16 + s)*64 + lane)*8 + j ;  value = Wm1[16s + (lane>>5)*8 + j][32wc + (lane&31)]
__global__ __launch_bounds__(256) void pack_wm1_kernel(const float* __restrict__ Wm1,
                                                       unsigned short* __restrict__ phi,
                                                       unsigned short* __restrict__ plo) {
    int t = blockIdx.x * 256 + threadIdx.x;  // 0..32767
    int j = t & 7;
    int lane = (t >> 3) & 63;
    int s = (t >> 9) & 15;
    int wc = t >> 13;
    int k = 16 * s + ((lane >> 5) << 3) + j;
    int n = 32 * wc + (lane & 31);
    float f = Wm1[k * 128 + n];
    unsigned short h = f2bf(f);
    phi[t] = h;
    float fh = __uint_as_float((unsigned int)h << 16);
    plo[t] = f2bf(f - fh);
}

// ---------------------------------------------------------------------------
// Edge MLP via split-bf16 MFMA. 32 edges/block, 4 waves = 4 col-tiles of 32.
// acc += Ahi*Bhi + Alo*Bhi + Ahi*Blo  (~fp32 precision).
// hid never hits global memory.
// ---------------------------------------------------------------------------
__global__ __launch_bounds__(256) void edge_mlp_mfma_kernel(
    const unsigned short* __restrict__ h2hi, const unsigned short* __restrict__ h2lo,
    const int* __restrict__ src, const int* __restrict__ dst,
    const unsigned short* __restrict__ wphi, const unsigned short* __restrict__ wplo,
    const float* __restrict__ bm1, const float* __restrict__ Wm2,
    const float* __restrict__ bm2, float* __restrict__ out) {
    __shared__ __align__(16) unsigned short efhi[32 * 256];
    __shared__ __align__(16) unsigned short eflo[32 * 256];
    __shared__ int nodes[64];
    __shared__ float red[32 * 4];
    int tid = threadIdx.x;
    int e0 = blockIdx.x * 32;  // 800000 % 32 == 0: no bounds checks needed
    if (tid < 64) nodes[tid] = (tid < 32) ? src[e0 + tid] : dst[e0 + tid - 32];
    __syncthreads();

    // Stage EF (32 edges x 256 k) hi/lo into LDS in A-fragment order with XOR swizzle.
    // Writer i: e = i>>5 (edge), c = i&31 (16B chunk). Chunks 0-15 = src row, 16-31 = dst row.
    // Logical granule g = (c>>1)*64 + (c&1)*32 + e ; phys = g ^ ((c>>1)&7).
#pragma unroll
    for (int iter = 0; iter < 4; iter++) {
        int i = iter * 256 + tid;
        int e = i >> 5;
        int c = i & 31;
        int node = nodes[((c >> 4) << 5) | e];
        int fo = node * 128 + (c & 15) * 8;
        int g = ((c >> 1) * 64 + (c & 1) * 32 + e) ^ ((c >> 1) & 7);
        *(bf16x8*)&efhi[g * 8] = *(const bf16x8*)&h2hi[fo];
        *(bf16x8*)&eflo[g * 8] = *(const bf16x8*)&h2lo[fo];
    }
    __syncthreads();

    int wave = tid >> 6, lane = tid & 63;
    f32x16 acc = {};
    const bf16x8* bph = (const bf16x8*)wphi + wave * 16 * 64 + lane;
    const bf16x8* bpl = (const bf16x8*)wplo + wave * 16 * 64 + lane;
#pragma unroll
    for (int s = 0; s < 16; s++) {
        bf16x8 bh = bph[s * 64];
        bf16x8 bl = bpl[s * 64];
        int g = (s * 64 + lane) ^ (s & 7);
        bf16x8 ah = *(const bf16x8*)&efhi[g * 8];
        bf16x8 al = *(const bf16x8*)&eflo[g * 8];
        acc = __builtin_amdgcn_mfma_f32_32x32x16_bf16(ah, bh, acc, 0, 0, 0);
        acc = __builtin_amdgcn_mfma_f32_32x32x16_bf16(al, bh, acc, 0, 0, 0);
        acc = __builtin_amdgcn_mfma_f32_32x32x16_bf16(ah, bl, acc, 0, 0, 0);
    }

    // Epilogue: h = relu(acc + bm1[col]); p = h*Wm2[col]; reduce over cols.
    int col = wave * 32 + (lane & 31);
    float b1v = bm1[col];
    float w2v = Wm2[col];
    float rs[16];
#pragma unroll
    for (int r = 0; r < 16; r++) {
        float p = fmaxf(acc[r] + b1v, 0.f) * w2v;
        p += __shfl_xor(p, 1);
        p += __shfl_xor(p, 2);
        p += __shfl_xor(p, 4);
        p += __shfl_xor(p, 8);
        p += __shfl_xor(p, 16);
        rs[r] = p;
    }
    if ((lane & 31) == 0) {
        int half = lane >> 5;
#pragma unroll
        for (int r = 0; r < 16; r++) {
            int row = (r & 3) + 8 * (r >> 2) + 4 * half;  // C/D row mapping (m74/m101)
            red[row * 4 + wave] = rs[r];
        }
    }
    __syncthreads();
    if (tid < 32) {
        out[e0 + tid] = red[tid * 4 + 0] + red[tid * 4 + 1] + red[tid * 4 + 2] +
                        red[tid * 4 + 3] + bm2[0];
    }
}

// ---------------------------------------------------------------------------
extern "C" void kernel_launch(void* const* d_in, const int* in_sizes, int n_in,
                              void* d_out, int out_size, void* d_ws, size_t ws_size,
                              hipStream_t stream) {
    const float* x    = (const float*)d_in[0];
    const int* eidx   = (const int*)d_in[1];
    const float* W_in = (const float*)d_in[2];
    const float* b_in = (const float*)d_in[3];
    const float* W1   = (const float*)d_in[4];
    const float* b1   = (const float*)d_in[5];
    const float* W2   = (const float*)d_in[6];
    const float* b2   = (const float*)d_in[7];
    const float* Wm1  = (const float*)d_in[8];
    const float* bm1  = (const float*)d_in[9];
    const float* Wm2  = (const float*)d_in[10];
    const float* bm2  = (const float*)d_in[11];
    float* out = (float*)d_out;
    const int* src = eidx;
    const int* dst = eidx + N_EDGES;

    char* w = (char*)d_ws;
    size_t off = 0;
    auto alloc = [&](size_t bytes) -> char* {
        char* p = w + off;
        off = (off + bytes + 255) & ~(size_t)255;
        return p;
    };
    int* cnt      = (int*)alloc((size_t)N_NODES * 4);
    int* csr_ptr  = (int*)alloc((size_t)(N_NODES + 1) * 4);
    int* cursor   = (int*)alloc((size_t)N_NODES * 4);
    float* dinv   = (float*)alloc((size_t)N_NODES * 4);
    int* csr_src  = (int*)alloc((size_t)N_EDGES * 4);
    float* bufA   = (float*)alloc((size_t)N_NODES * HID * 4);
    float* bufB   = (float*)alloc((size_t)N_NODES * HID * 4);
    unsigned short* wphi = (unsigned short*)alloc((size_t)256 * 128 * 2);
    unsigned short* wplo = (unsigned short*)alloc((size_t)256 * 128 * 2);
    // h2 hi/lo bf16 reuse bufB's space after xw2 is consumed
    unsigned short* h2hi = (unsigned short*)bufB;
    unsigned short* h2lo = h2hi + (size_t)N_NODES * HID;

    hipMemsetAsync(cnt, 0, (size_t)N_NODES * 4, stream);
    count_kernel<<<(N_EDGES + 255) / 256, 256, 0, stream>>>(dst, cnt, N_EDGES);
    scan_kernel<<<1, 1024, 0, stream>>>(cnt, csr_ptr, cursor, dinv, N_NODES);
    fill_kernel<<<(N_EDGES + 255) / 256, 256, 0, stream>>>(src, dst, cursor, csr_src, N_EDGES);
    pack_wm1_kernel<<<128, 256, 0, stream>>>(Wm1, wphi, wplo);

    // h0 = relu(x @ W_in + b_in)                -> bufA
    gemm_kernel<<<(N_NODES + 31) / 32, 256, 0, stream>>>(x, W_in, b_in, bufA, N_NODES, D_IN, 1);
    // xw1 = h0 @ W1                             -> bufB
    gemm_kernel<<<(N_NODES + 31) / 32, 256, 0, stream>>>(bufA, W1, nullptr, bufB, N_NODES, HID, 0);
    // h1 = relu(aggregate(xw1) + b1)            -> bufA
    aggregate_kernel<<<N_NODES, 128, 0, stream>>>(bufB, dinv, csr_ptr, csr_src, b1, bufA);
    // xw2 = h1 @ W2                             -> bufB  (then h1 no longer needed... but bufA holds h1, xw2 -> bufB)
    gemm_kernel<<<(N_NODES + 31) / 32, 256, 0, stream>>>(bufA, W2, nullptr, bufB, N_NODES, HID, 0);
    // h2 = relu(aggregate(xw2) + b2): xw2 in bufB is fully read before any write of h2w?
    // aggregate reads bufB randomly while writing bufA -> safe (different buffers).
    aggregate_kernel<<<N_NODES, 128, 0, stream>>>(bufB, dinv, csr_ptr, csr_src, b2, bufA);
    // split h2 (bufA) into bf16 hi/lo — stored in bufB space (xw2 dead now)
    split_bf16_kernel<<<(N_NODES * HID + 255) / 256, 256, 0, stream>>>(bufA, h2hi, h2lo, N_NODES * HID);
    // logits
    edge_mlp_mfma_kernel<<<N_EDGES / 32, 256, 0, stream>>>(h2hi, h2lo, src, dst, wphi, wplo,
                                                           bm1, Wm2, bm2, out);
}

// Round 3
// 682.067 us; speedup vs baseline: 1.7920x; 1.2130x over previous
//
#include <hip/hip_runtime.h>

#define N_NODES 50000
#define N_EDGES 800000
#define D_IN 96
#define HID 128

// ---------------------------------------------------------------------------
// CSR build: count in-degree, exclusive scan (single block), fill edge ids.
// ---------------------------------------------------------------------------
__global__ void count_kernel(const int* __restrict__ dst, int* __restrict__ cnt, int E) {
    int e = blockIdx.x * 256 + threadIdx.x;
    if (e < E) atomicAdd(&cnt[dst[e]], 1);
}

__global__ __launch_bounds__(1024) void scan_kernel(const int* __restrict__ cnt,
                                                    int* __restrict__ csr_ptr,
                                                    int* __restrict__ cursor,
                                                    float* __restrict__ dinv,
                                                    int N) {
    __shared__ int part[1024];
    const int CH = 49;
    int t = threadIdx.x;
    int start = t * CH;
    int end = min(start + CH, N);
    int s = 0;
    for (int i = start; i < end; i++) s += cnt[i];
    part[t] = s;
    __syncthreads();
    for (int off = 1; off < 1024; off <<= 1) {
        int v = (t >= off) ? part[t - off] : 0;
        __syncthreads();
        part[t] += v;
        __syncthreads();
    }
    int run = part[t] - s;
    for (int i = start; i < end; i++) {
        csr_ptr[i] = run;
        cursor[i] = run;
        int c = cnt[i];
        dinv[i] = 1.0f / sqrtf((float)(c + 1));
        run += c;
    }
    if (t == 1023) csr_ptr[N] = part[1023];
}

// Fill CSR-ordered edge arrays: src node, dst node, original edge id.
__global__ void fill_kernel(const int* __restrict__ src, const int* __restrict__ dst,
                            int* __restrict__ cursor,
                            int* __restrict__ ce_src, int* __restrict__ ce_dst,
                            int* __restrict__ ce_eid, int E) {
    int e = blockIdx.x * 256 + threadIdx.x;
    if (e < E) {
        int d = dst[e];
        int pos = atomicAdd(&cursor[d], 1);
        ce_src[pos] = src[e];
        ce_dst[pos] = d;
        ce_eid[pos] = e;
    }
}

// ---------------------------------------------------------------------------
// Node GEMM: out[M][128] = (in[M][K] @ W[K][128] + bias) (relu / rowscale opt)
// rowscale: out_row *= rowscale[row] (applied after bias; used with bias=null)
// ---------------------------------------------------------------------------
__global__ __launch_bounds__(256) void gemm_kernel(const float* __restrict__ in,
                                                   const float* __restrict__ W,
                                                   const float* __restrict__ bias,
                                                   const float* __restrict__ rowscale,
                                                   float* __restrict__ out,
                                                   int M, int K, int dorelu) {
    __shared__ float xs[32 * 128];
    int tid = threadIdx.x;
    int M0 = blockIdx.x * 32;
    int K4 = K >> 2;
    for (int i = tid; i < 32 * K4; i += 256) {
        int r = i / K4, c4 = i - r * K4;
        float4 v = make_float4(0.f, 0.f, 0.f, 0.f);
        if (M0 + r < M) v = *(const float4*)&in[(size_t)(M0 + r) * K + c4 * 4];
        *(float4*)&xs[r * K + c4 * 4] = v;
    }
    __syncthreads();
    int col = tid & 127, rg = tid >> 7;
    float acc[16];
#pragma unroll
    for (int r = 0; r < 16; r++) acc[r] = 0.f;
    const float* xb = &xs[rg * 16 * K];
    for (int k4 = 0; k4 < K4; k4++) {
        float w0 = W[(k4 * 4 + 0) * 128 + col];
        float w1 = W[(k4 * 4 + 1) * 128 + col];
        float w2 = W[(k4 * 4 + 2) * 128 + col];
        float w3 = W[(k4 * 4 + 3) * 128 + col];
#pragma unroll
        for (int r = 0; r < 16; r++) {
            float4 a = *(const float4*)&xb[r * K + k4 * 4];
            acc[r] = fmaf(a.x, w0, acc[r]);
            acc[r] = fmaf(a.y, w1, acc[r]);
            acc[r] = fmaf(a.z, w2, acc[r]);
            acc[r] = fmaf(a.w, w3, acc[r]);
        }
    }
    float bv = bias ? bias[col] : 0.f;
#pragma unroll
    for (int r = 0; r < 16; r++) {
        int row = M0 + rg * 16 + r;
        if (row < M) {
            float v = acc[r] + bv;
            if (rowscale) v *= rowscale[row];
            if (dorelu) v = fmaxf(v, 0.f);
            out[(size_t)row * 128 + col] = v;
        }
    }
}

__device__ inline unsigned short f2bf(float f) {
    unsigned int u = __float_as_uint(f);
    return (unsigned short)((u + 0x7fffu + ((u >> 16) & 1u)) >> 16);
}

// Same GEMM but bf16 output (for U/V edge-factor tables).
__global__ __launch_bounds__(256) void gemm_bf16out_kernel(const float* __restrict__ in,
                                                           const float* __restrict__ W,
                                                           const float* __restrict__ bias,
                                                           unsigned short* __restrict__ out,
                                                           int M, int K) {
    __shared__ float xs[32 * 128];
    int tid = threadIdx.x;
    int M0 = blockIdx.x * 32;
    int K4 = K >> 2;
    for (int i = tid; i < 32 * K4; i += 256) {
        int r = i / K4, c4 = i - r * K4;
        float4 v = make_float4(0.f, 0.f, 0.f, 0.f);
        if (M0 + r < M) v = *(const float4*)&in[(size_t)(M0 + r) * K + c4 * 4];
        *(float4*)&xs[r * K + c4 * 4] = v;
    }
    __syncthreads();
    int col = tid & 127, rg = tid >> 7;
    float acc[16];
#pragma unroll
    for (int r = 0; r < 16; r++) acc[r] = 0.f;
    const float* xb = &xs[rg * 16 * K];
    for (int k4 = 0; k4 < K4; k4++) {
        float w0 = W[(k4 * 4 + 0) * 128 + col];
        float w1 = W[(k4 * 4 + 1) * 128 + col];
        float w2 = W[(k4 * 4 + 2) * 128 + col];
        float w3 = W[(k4 * 4 + 3) * 128 + col];
#pragma unroll
        for (int r = 0; r < 16; r++) {
            float4 a = *(const float4*)&xb[r * K + k4 * 4];
            acc[r] = fmaf(a.x, w0, acc[r]);
            acc[r] = fmaf(a.y, w1, acc[r]);
            acc[r] = fmaf(a.z, w2, acc[r]);
            acc[r] = fmaf(a.w, w3, acc[r]);
        }
    }
    float bv = bias ? bias[col] : 0.f;
#pragma unroll
    for (int r = 0; r < 16; r++) {
        int row = M0 + rg * 16 + r;
        if (row < M) out[(size_t)row * 128 + col] = f2bf(acc[r] + bv);
    }
}

// ---------------------------------------------------------------------------
// GCN aggregation, wave-per-node. y = xw * dinv[row] (prescaled in GEMM).
// out[i][c] = relu( dinv[i] * (y[i][c] + sum_{e:dst=i} y[src_e][c]) + b[c] )
// One wave (64 lanes) per node, 2 cols per lane, 4-way unrolled gather.
// ---------------------------------------------------------------------------
__global__ __launch_bounds__(256) void aggregate_kernel(const float* __restrict__ y,
                                                        const float* __restrict__ dinv,
                                                        const int* __restrict__ ptr,
                                                        const int* __restrict__ csrc,
                                                        const float* __restrict__ bias,
                                                        float* __restrict__ out) {
    int node = blockIdx.x * 4 + (threadIdx.x >> 6);
    int lane = threadIdx.x & 63;
    int c = lane * 2;
    float di = dinv[node];
    float2 self = *(const float2*)&y[(size_t)node * 128 + c];
    float a0 = self.x, a1 = self.y;
    float b0 = 0.f, b1 = 0.f, c0 = 0.f, c1 = 0.f, d0 = 0.f, d1 = 0.f;
    int s0 = ptr[node], s1 = ptr[node + 1];
    int j = s0;
    for (; j + 3 < s1; j += 4) {
        int n0 = csrc[j], n1 = csrc[j + 1], n2 = csrc[j + 2], n3 = csrc[j + 3];
        float2 v0 = *(const float2*)&y[(size_t)n0 * 128 + c];
        float2 v1 = *(const float2*)&y[(size_t)n1 * 128 + c];
        float2 v2 = *(const float2*)&y[(size_t)n2 * 128 + c];
        float2 v3 = *(const float2*)&y[(size_t)n3 * 128 + c];
        a0 += v0.x; a1 += v0.y;
        b0 += v1.x; b1 += v1.y;
        c0 += v2.x; c1 += v2.y;
        d0 += v3.x; d1 += v3.y;
    }
    for (; j < s1; j++) {
        int n = csrc[j];
        float2 v = *(const float2*)&y[(size_t)n * 128 + c];
        a0 += v.x; a1 += v.y;
    }
    float2 bv = *(const float2*)&bias[c];
    float o0 = fmaxf(di * (a0 + b0 + c0 + d0) + bv.x, 0.f);
    float o1 = fmaxf(di * (a1 + b1 + c1 + d1) + bv.y, 0.f);
    *(float2*)&out[(size_t)node * 128 + c] = make_float2(o0, o1);
}

// ---------------------------------------------------------------------------
// Edge MLP via U/V decomposition:
//   hid = relu(U[src] + V[dst]), logit = hid . Wm2 + bm2
// U = h2@Wm1[:128] + bm1, V = h2@Wm1[128:], both bf16 [N_NODES x 128].
// Edges processed in CSR (dst-sorted) order: V gathers are L1-hot.
// 16 lanes per edge, 8 cols per lane; 4-level shfl reduction.
// ---------------------------------------------------------------------------
__global__ __launch_bounds__(256) void edge_mlp_kernel(const unsigned short* __restrict__ Ub,
                                                       const unsigned short* __restrict__ Vb,
                                                       const int* __restrict__ ce_src,
                                                       const int* __restrict__ ce_dst,
                                                       const int* __restrict__ ce_eid,
                                                       const float* __restrict__ Wm2,
                                                       const float* __restrict__ bm2,
                                                       float* __restrict__ out) {
    __shared__ int sm[48];
    int tid = threadIdx.x;
    int e0 = blockIdx.x * 16;
    if (tid < 48) {
        int w = tid >> 4, i = tid & 15;
        const int* p = (w == 0) ? ce_src : (w == 1) ? ce_dst : ce_eid;
        sm[tid] = p[e0 + i];
    }
    __syncthreads();
    int g = tid >> 4;   // local edge 0..15
    int l = tid & 15;   // lane within edge group; cols l*8 .. l*8+7
    int srcn = sm[g];
    int dstn = sm[16 + g];
    uint4 u = *(const uint4*)&Ub[(size_t)srcn * 128 + l * 8];
    uint4 v = *(const uint4*)&Vb[(size_t)dstn * 128 + l * 8];
    float4 w0 = *(const float4*)&Wm2[l * 8];
    float4 w1 = *(const float4*)&Wm2[l * 8 + 4];
    float p = 0.f;
    {
        unsigned int uu, vv;
        float ua, va;
#define TERM(UU, VV, WLO, WHI)                                   \
        uu = (UU); vv = (VV);                                     \
        ua = __uint_as_float(uu << 16);                           \
        va = __uint_as_float(vv << 16);                           \
        p = fmaf(fmaxf(ua + va, 0.f), (WLO), p);                  \
        ua = __uint_as_float(uu & 0xffff0000u);                   \
        va = __uint_as_float(vv & 0xffff0000u);                   \
        p = fmaf(fmaxf(ua + va, 0.f), (WHI), p);
        TERM(u.x, v.x, w0.x, w0.y)
        TERM(u.y, v.y, w0.z, w0.w)
        TERM(u.z, v.z, w1.x, w1.y)
        TERM(u.w, v.w, w1.z, w1.w)
#undef TERM
    }
    p += __shfl_xor(p, 1);
    p += __shfl_xor(p, 2);
    p += __shfl_xor(p, 4);
    p += __shfl_xor(p, 8);
    if (l == 0) out[sm[32 + g]] = p + bm2[0];
}

// ---------------------------------------------------------------------------
extern "C" void kernel_launch(void* const* d_in, const int* in_sizes, int n_in,
                              void* d_out, int out_size, void* d_ws, size_t ws_size,
                              hipStream_t stream) {
    const float* x    = (const float*)d_in[0];
    const int* eidx   = (const int*)d_in[1];
    const float* W_in = (const float*)d_in[2];
    const float* b_in = (const float*)d_in[3];
    const float* W1   = (const float*)d_in[4];
    const float* b1   = (const float*)d_in[5];
    const float* W2   = (const float*)d_in[6];
    const float* b2   = (const float*)d_in[7];
    const float* Wm1  = (const float*)d_in[8];
    const float* bm1  = (const float*)d_in[9];
    const float* Wm2  = (const float*)d_in[10];
    const float* bm2  = (const float*)d_in[11];
    float* out = (float*)d_out;
    const int* src = eidx;
    const int* dst = eidx + N_EDGES;

    char* w = (char*)d_ws;
    size_t off = 0;
    auto alloc = [&](size_t bytes) -> char* {
        char* p = w + off;
        off = (off + bytes + 255) & ~(size_t)255;
        return p;
    };
    int* cnt      = (int*)alloc((size_t)N_NODES * 4);
    int* csr_ptr  = (int*)alloc((size_t)(N_NODES + 1) * 4);
    int* cursor   = (int*)alloc((size_t)N_NODES * 4);
    float* dinv   = (float*)alloc((size_t)N_NODES * 4);
    int* ce_src   = (int*)alloc((size_t)N_EDGES * 4);
    int* ce_dst   = (int*)alloc((size_t)N_EDGES * 4);
    int* ce_eid   = (int*)alloc((size_t)N_EDGES * 4);
    float* bufA   = (float*)alloc((size_t)N_NODES * HID * 4);
    float* bufB   = (float*)alloc((size_t)N_NODES * HID * 4);
    // U/V bf16 tables overlay bufB (y2 is dead once h2 is computed)
    unsigned short* Ub = (unsigned short*)bufB;
    unsigned short* Vb = Ub + (size_t)N_NODES * HID;

    hipMemsetAsync(cnt, 0, (size_t)N_NODES * 4, stream);
    count_kernel<<<(N_EDGES + 255) / 256, 256, 0, stream>>>(dst, cnt, N_EDGES);
    scan_kernel<<<1, 1024, 0, stream>>>(cnt, csr_ptr, cursor, dinv, N_NODES);
    fill_kernel<<<(N_EDGES + 255) / 256, 256, 0, stream>>>(src, dst, cursor,
                                                           ce_src, ce_dst, ce_eid, N_EDGES);

    // h0 = relu(x @ W_in + b_in)                    -> bufA
    gemm_kernel<<<(N_NODES + 31) / 32, 256, 0, stream>>>(x, W_in, b_in, nullptr, bufA,
                                                         N_NODES, D_IN, 1);
    // y1 = (h0 @ W1) * dinv[row]                    -> bufB
    gemm_kernel<<<(N_NODES + 31) / 32, 256, 0, stream>>>(bufA, W1, nullptr, dinv, bufB,
                                                         N_NODES, HID, 0);
    // h1 = relu(dinv*(y1_self + sum y1[src]) + b1)  -> bufA
    aggregate_kernel<<<N_NODES / 4, 256, 0, stream>>>(bufB, dinv, csr_ptr, ce_src, b1, bufA);
    // y2 = (h1 @ W2) * dinv[row]                    -> bufB
    gemm_kernel<<<(N_NODES + 31) / 32, 256, 0, stream>>>(bufA, W2, nullptr, dinv, bufB,
                                                         N_NODES, HID, 0);
    // h2 = relu(dinv*(y2_self + sum y2[src]) + b2)  -> bufA
    aggregate_kernel<<<N_NODES / 4, 256, 0, stream>>>(bufB, dinv, csr_ptr, ce_src, b2, bufA);
    // U = h2 @ Wm1[:128] + bm1 (bf16)               -> Ub (overlays bufB)
    gemm_bf16out_kernel<<<(N_NODES + 31) / 32, 256, 0, stream>>>(bufA, Wm1, bm1, Ub,
                                                                 N_NODES, HID);
    // V = h2 @ Wm1[128:] (bf16)                     -> Vb
    gemm_bf16out_kernel<<<(N_NODES + 31) / 32, 256, 0, stream>>>(bufA, Wm1 + 128 * 128,
                                                                 nullptr, Vb, N_NODES, HID);
    // logits (CSR order, scatter by original edge id)
    edge_mlp_kernel<<<N_EDGES / 16, 256, 0, stream>>>(Ub, Vb, ce_src, ce_dst, ce_eid,
                                                      Wm2, bm2, out);
}

// Round 4
// 553.735 us; speedup vs baseline: 2.2073x; 1.2318x over previous
//
#include <hip/hip_runtime.h>

#define N_NODES 50000
#define N_EDGES 800000
#define D_IN 96
#define HID 128
#define SCAN_BLOCKS ((N_NODES + 255) / 256)   // 196

// ---------------------------------------------------------------------------
// CSR build: count, 3-stage parallel exclusive scan, fill.
// ---------------------------------------------------------------------------
__global__ void count_kernel(const int* __restrict__ dst, int* __restrict__ cnt, int E) {
    int e = blockIdx.x * 256 + threadIdx.x;
    if (e < E) atomicAdd(&cnt[dst[e]], 1);
}

// Stage 1: per-block sums of cnt (256 elements per block).
__global__ __launch_bounds__(256) void block_sum_kernel(const int* __restrict__ cnt,
                                                        int* __restrict__ bsum, int N) {
    int i = blockIdx.x * 256 + threadIdx.x;
    int c = (i < N) ? cnt[i] : 0;
#pragma unroll
    for (int off = 1; off < 64; off <<= 1) c += __shfl_xor(c, off);
    __shared__ int s[4];
    int wave = threadIdx.x >> 6;
    if ((threadIdx.x & 63) == 0) s[wave] = c;
    __syncthreads();
    if (threadIdx.x == 0) bsum[blockIdx.x] = s[0] + s[1] + s[2] + s[3];
}

// Stage 2: single small block scans the partials (exclusive), writes total.
__global__ __launch_bounds__(256) void scan_partials_kernel(const int* __restrict__ bsum,
                                                            int* __restrict__ boff,
                                                            int* __restrict__ csr_ptr) {
    __shared__ int s[256];
    int t = threadIdx.x;
    int v = (t < SCAN_BLOCKS) ? bsum[t] : 0;
    s[t] = v;
    __syncthreads();
    for (int off = 1; off < 256; off <<= 1) {
        int u = (t >= off) ? s[t - off] : 0;
        __syncthreads();
        s[t] += u;
        __syncthreads();
    }
    if (t < SCAN_BLOCKS) boff[t] = s[t] - v;  // exclusive
    if (t == 255) csr_ptr[N_NODES] = s[255];
}

// Stage 3: per-block local inclusive scan + block offset -> csr_ptr/cursor/dinv.
__global__ __launch_bounds__(256) void scan_scatter_kernel(const int* __restrict__ cnt,
                                                           const int* __restrict__ boff,
                                                           int* __restrict__ csr_ptr,
                                                           int* __restrict__ cursor,
                                                           float* __restrict__ dinv, int N) {
    __shared__ int s[256];
    int t = threadIdx.x;
    int i = blockIdx.x * 256 + t;
    int c = (i < N) ? cnt[i] : 0;
    s[t] = c;
    __syncthreads();
    for (int off = 1; off < 256; off <<= 1) {
        int u = (t >= off) ? s[t - off] : 0;
        __syncthreads();
        s[t] += u;
        __syncthreads();
    }
    if (i < N) {
        int run = boff[blockIdx.x] + s[t] - c;  // exclusive position
        csr_ptr[i] = run;
        cursor[i] = run;
        dinv[i] = 1.0f / sqrtf((float)(c + 1));
    }
}

// Fill CSR-ordered edge arrays: src node, dst node, original edge id.
__global__ void fill_kernel(const int* __restrict__ src, const int* __restrict__ dst,
                            int* __restrict__ cursor,
                            int* __restrict__ ce_src, int* __restrict__ ce_dst,
                            int* __restrict__ ce_eid, int E) {
    int e = blockIdx.x * 256 + threadIdx.x;
    if (e < E) {
        int d = dst[e];
        int pos = atomicAdd(&cursor[d], 1);
        ce_src[pos] = src[e];
        ce_dst[pos] = d;
        ce_eid[pos] = e;
    }
}

// ---------------------------------------------------------------------------
// Node GEMM: out[M][128] = (in[M][K] @ W[K][128] + bias) (relu / rowscale opt)
// ---------------------------------------------------------------------------
__global__ __launch_bounds__(256) void gemm_kernel(const float* __restrict__ in,
                                                   const float* __restrict__ W,
                                                   const float* __restrict__ bias,
                                                   const float* __restrict__ rowscale,
                                                   float* __restrict__ out,
                                                   int M, int K, int dorelu) {
    __shared__ float xs[32 * 128];
    int tid = threadIdx.x;
    int M0 = blockIdx.x * 32;
    int K4 = K >> 2;
    for (int i = tid; i < 32 * K4; i += 256) {
        int r = i / K4, c4 = i - r * K4;
        float4 v = make_float4(0.f, 0.f, 0.f, 0.f);
        if (M0 + r < M) v = *(const float4*)&in[(size_t)(M0 + r) * K + c4 * 4];
        *(float4*)&xs[r * K + c4 * 4] = v;
    }
    __syncthreads();
    int col = tid & 127, rg = tid >> 7;
    float acc[16];
#pragma unroll
    for (int r = 0; r < 16; r++) acc[r] = 0.f;
    const float* xb = &xs[rg * 16 * K];
    for (int k4 = 0; k4 < K4; k4++) {
        float w0 = W[(k4 * 4 + 0) * 128 + col];
        float w1 = W[(k4 * 4 + 1) * 128 + col];
        float w2 = W[(k4 * 4 + 2) * 128 + col];
        float w3 = W[(k4 * 4 + 3) * 128 + col];
#pragma unroll
        for (int r = 0; r < 16; r++) {
            float4 a = *(const float4*)&xb[r * K + k4 * 4];
            acc[r] = fmaf(a.x, w0, acc[r]);
            acc[r] = fmaf(a.y, w1, acc[r]);
            acc[r] = fmaf(a.z, w2, acc[r]);
            acc[r] = fmaf(a.w, w3, acc[r]);
        }
    }
    float bv = bias ? bias[col] : 0.f;
#pragma unroll
    for (int r = 0; r < 16; r++) {
        int row = M0 + rg * 16 + r;
        if (row < M) {
            float v = acc[r] + bv;
            if (rowscale) v *= rowscale[row];
            if (dorelu) v = fmaxf(v, 0.f);
            out[(size_t)row * 128 + col] = v;
        }
    }
}

__device__ inline unsigned short f2bf(float f) {
    unsigned int u = __float_as_uint(f);
    return (unsigned short)((u + 0x7fffu + ((u >> 16) & 1u)) >> 16);
}

// Same GEMM but bf16 output (for U/V edge-factor tables).
__global__ __launch_bounds__(256) void gemm_bf16out_kernel(const float* __restrict__ in,
                                                           const float* __restrict__ W,
                                                           const float* __restrict__ bias,
                                                           unsigned short* __restrict__ out,
                                                           int M, int K) {
    __shared__ float xs[32 * 128];
    int tid = threadIdx.x;
    int M0 = blockIdx.x * 32;
    int K4 = K >> 2;
    for (int i = tid; i < 32 * K4; i += 256) {
        int r = i / K4, c4 = i - r * K4;
        float4 v = make_float4(0.f, 0.f, 0.f, 0.f);
        if (M0 + r < M) v = *(const float4*)&in[(size_t)(M0 + r) * K + c4 * 4];
        *(float4*)&xs[r * K + c4 * 4] = v;
    }
    __syncthreads();
    int col = tid & 127, rg = tid >> 7;
    float acc[16];
#pragma unroll
    for (int r = 0; r < 16; r++) acc[r] = 0.f;
    const float* xb = &xs[rg * 16 * K];
    for (int k4 = 0; k4 < K4; k4++) {
        float w0 = W[(k4 * 4 + 0) * 128 + col];
        float w1 = W[(k4 * 4 + 1) * 128 + col];
        float w2 = W[(k4 * 4 + 2) * 128 + col];
        float w3 = W[(k4 * 4 + 3) * 128 + col];
#pragma unroll
        for (int r = 0; r < 16; r++) {
            float4 a = *(const float4*)&xb[r * K + k4 * 4];
            acc[r] = fmaf(a.x, w0, acc[r]);
            acc[r] = fmaf(a.y, w1, acc[r]);
            acc[r] = fmaf(a.z, w2, acc[r]);
            acc[r] = fmaf(a.w, w3, acc[r]);
        }
    }
    float bv = bias ? bias[col] : 0.f;
#pragma unroll
    for (int r = 0; r < 16; r++) {
        int row = M0 + rg * 16 + r;
        if (row < M) out[(size_t)row * 128 + col] = f2bf(acc[r] + bv);
    }
}

// ---------------------------------------------------------------------------
// GCN aggregation, wave-per-node, 4-way unrolled gather.
// ---------------------------------------------------------------------------
__global__ __launch_bounds__(256) void aggregate_kernel(const float* __restrict__ y,
                                                        const float* __restrict__ dinv,
                                                        const int* __restrict__ ptr,
                                                        const int* __restrict__ csrc,
                                                        const float* __restrict__ bias,
                                                        float* __restrict__ out) {
    int node = blockIdx.x * 4 + (threadIdx.x >> 6);
    int lane = threadIdx.x & 63;
    int c = lane * 2;
    float di = dinv[node];
    float2 self = *(const float2*)&y[(size_t)node * 128 + c];
    float a0 = self.x, a1 = self.y;
    float b0 = 0.f, b1 = 0.f, c0 = 0.f, c1 = 0.f, d0 = 0.f, d1 = 0.f;
    int s0 = ptr[node], s1 = ptr[node + 1];
    int j = s0;
    for (; j + 3 < s1; j += 4) {
        int n0 = csrc[j], n1 = csrc[j + 1], n2 = csrc[j + 2], n3 = csrc[j + 3];
        float2 v0 = *(const float2*)&y[(size_t)n0 * 128 + c];
        float2 v1 = *(const float2*)&y[(size_t)n1 * 128 + c];
        float2 v2 = *(const float2*)&y[(size_t)n2 * 128 + c];
        float2 v3 = *(const float2*)&y[(size_t)n3 * 128 + c];
        a0 += v0.x; a1 += v0.y;
        b0 += v1.x; b1 += v1.y;
        c0 += v2.x; c1 += v2.y;
        d0 += v3.x; d1 += v3.y;
    }
    for (; j < s1; j++) {
        int n = csrc[j];
        float2 v = *(const float2*)&y[(size_t)n * 128 + c];
        a0 += v.x; a1 += v.y;
    }
    float2 bv = *(const float2*)&bias[c];
    float o0 = fmaxf(di * (a0 + b0 + c0 + d0) + bv.x, 0.f);
    float o1 = fmaxf(di * (a1 + b1 + c1 + d1) + bv.y, 0.f);
    *(float2*)&out[(size_t)node * 128 + c] = make_float2(o0, o1);
}

// ---------------------------------------------------------------------------
// Edge MLP via U/V decomposition (CSR order; V gathers L1-hot).
// ---------------------------------------------------------------------------
__global__ __launch_bounds__(256) void edge_mlp_kernel(const unsigned short* __restrict__ Ub,
                                                       const unsigned short* __restrict__ Vb,
                                                       const int* __restrict__ ce_src,
                                                       const int* __restrict__ ce_dst,
                                                       const int* __restrict__ ce_eid,
                                                       const float* __restrict__ Wm2,
                                                       const float* __restrict__ bm2,
                                                       float* __restrict__ out) {
    __shared__ int sm[48];
    int tid = threadIdx.x;
    int e0 = blockIdx.x * 16;
    if (tid < 48) {
        int w = tid >> 4, i = tid & 15;
        const int* p = (w == 0) ? ce_src : (w == 1) ? ce_dst : ce_eid;
        sm[tid] = p[e0 + i];
    }
    __syncthreads();
    int g = tid >> 4;
    int l = tid & 15;
    int srcn = sm[g];
    int dstn = sm[16 + g];
    uint4 u = *(const uint4*)&Ub[(size_t)srcn * 128 + l * 8];
    uint4 v = *(const uint4*)&Vb[(size_t)dstn * 128 + l * 8];
    float4 w0 = *(const float4*)&Wm2[l * 8];
    float4 w1 = *(const float4*)&Wm2[l * 8 + 4];
    float p = 0.f;
    {
        unsigned int uu, vv;
        float ua, va;
#define TERM(UU, VV, WLO, WHI)                                   \
        uu = (UU); vv = (VV);                                     \
        ua = __uint_as_float(uu << 16);                           \
        va = __uint_as_float(vv << 16);                           \
        p = fmaf(fmaxf(ua + va, 0.f), (WLO), p);                  \
        ua = __uint_as_float(uu & 0xffff0000u);                   \
        va = __uint_as_float(vv & 0xffff0000u);                   \
        p = fmaf(fmaxf(ua + va, 0.f), (WHI), p);
        TERM(u.x, v.x, w0.x, w0.y)
        TERM(u.y, v.y, w0.z, w0.w)
        TERM(u.z, v.z, w1.x, w1.y)
        TERM(u.w, v.w, w1.z, w1.w)
#undef TERM
    }
    p += __shfl_xor(p, 1);
    p += __shfl_xor(p, 2);
    p += __shfl_xor(p, 4);
    p += __shfl_xor(p, 8);
    if (l == 0) out[sm[32 + g]] = p + bm2[0];
}

// ---------------------------------------------------------------------------
extern "C" void kernel_launch(void* const* d_in, const int* in_sizes, int n_in,
                              void* d_out, int out_size, void* d_ws, size_t ws_size,
                              hipStream_t stream) {
    const float* x    = (const float*)d_in[0];
    const int* eidx   = (const int*)d_in[1];
    const float* W_in = (const float*)d_in[2];
    const float* b_in = (const float*)d_in[3];
    const float* W1   = (const float*)d_in[4];
    const float* b1   = (const float*)d_in[5];
    const float* W2   = (const float*)d_in[6];
    const float* b2   = (const float*)d_in[7];
    const float* Wm1  = (const float*)d_in[8];
    const float* bm1  = (const float*)d_in[9];
    const float* Wm2  = (const float*)d_in[10];
    const float* bm2  = (const float*)d_in[11];
    float* out = (float*)d_out;
    const int* src = eidx;
    const int* dst = eidx + N_EDGES;

    char* w = (char*)d_ws;
    size_t off = 0;
    auto alloc = [&](size_t bytes) -> char* {
        char* p = w + off;
        off = (off + bytes + 255) & ~(size_t)255;
        return p;
    };
    int* cnt      = (int*)alloc((size_t)N_NODES * 4);
    int* csr_ptr  = (int*)alloc((size_t)(N_NODES + 1) * 4);
    int* cursor   = (int*)alloc((size_t)N_NODES * 4);
    float* dinv   = (float*)alloc((size_t)N_NODES * 4);
    int* bsum     = (int*)alloc((size_t)SCAN_BLOCKS * 4);
    int* boff     = (int*)alloc((size_t)SCAN_BLOCKS * 4);
    int* ce_src   = (int*)alloc((size_t)N_EDGES * 4);
    int* ce_dst   = (int*)alloc((size_t)N_EDGES * 4);
    int* ce_eid   = (int*)alloc((size_t)N_EDGES * 4);
    float* bufA   = (float*)alloc((size_t)N_NODES * HID * 4);
    float* bufB   = (float*)alloc((size_t)N_NODES * HID * 4);
    unsigned short* Ub = (unsigned short*)bufB;
    unsigned short* Vb = Ub + (size_t)N_NODES * HID;

    hipMemsetAsync(cnt, 0, (size_t)N_NODES * 4, stream);
    count_kernel<<<(N_EDGES + 255) / 256, 256, 0, stream>>>(dst, cnt, N_EDGES);
    block_sum_kernel<<<SCAN_BLOCKS, 256, 0, stream>>>(cnt, bsum, N_NODES);
    scan_partials_kernel<<<1, 256, 0, stream>>>(bsum, boff, csr_ptr);
    scan_scatter_kernel<<<SCAN_BLOCKS, 256, 0, stream>>>(cnt, boff, csr_ptr, cursor,
                                                         dinv, N_NODES);
    fill_kernel<<<(N_EDGES + 255) / 256, 256, 0, stream>>>(src, dst, cursor,
                                                           ce_src, ce_dst, ce_eid, N_EDGES);

    // h0 = relu(x @ W_in + b_in)                    -> bufA
    gemm_kernel<<<(N_NODES + 31) / 32, 256, 0, stream>>>(x, W_in, b_in, nullptr, bufA,
                                                         N_NODES, D_IN, 1);
    // y1 = (h0 @ W1) * dinv[row]                    -> bufB
    gemm_kernel<<<(N_NODES + 31) / 32, 256, 0, stream>>>(bufA, W1, nullptr, dinv, bufB,
                                                         N_NODES, HID, 0);
    // h1 = relu(dinv*(y1_self + sum y1[src]) + b1)  -> bufA
    aggregate_kernel<<<N_NODES / 4, 256, 0, stream>>>(bufB, dinv, csr_ptr, ce_src, b1, bufA);
    // y2 = (h1 @ W2) * dinv[row]                    -> bufB
    gemm_kernel<<<(N_NODES + 31) / 32, 256, 0, stream>>>(bufA, W2, nullptr, dinv, bufB,
                                                         N_NODES, HID, 0);
    // h2 = relu(dinv*(y2_self + sum y2[src]) + b2)  -> bufA
    aggregate_kernel<<<N_NODES / 4, 256, 0, stream>>>(bufB, dinv, csr_ptr, ce_src, b2, bufA);
    // U = h2 @ Wm1[:128] + bm1 (bf16)               -> Ub (overlays bufB)
    gemm_bf16out_kernel<<<(N_NODES + 31) / 32, 256, 0, stream>>>(bufA, Wm1, bm1, Ub,
                                                                 N_NODES, HID);
    // V = h2 @ Wm1[128:] (bf16)                     -> Vb
    gemm_bf16out_kernel<<<(N_NODES + 31) / 32, 256, 0, stream>>>(bufA, Wm1 + 128 * 128,
                                                                 nullptr, Vb, N_NODES, HID);
    // logits (CSR order, scatter by original edge id)
    edge_mlp_kernel<<<N_EDGES / 16, 256, 0, stream>>>(Ub, Vb, ce_src, ce_dst, ce_eid,
                                                      Wm2, bm2, out);
}

// Round 5
// 375.068 us; speedup vs baseline: 3.2588x; 1.4764x over previous
//
#include <hip/hip_runtime.h>

#define N_NODES 50000
#define N_EDGES 800000
#define D_IN 96
#define HID 128
#define SCAN_BLOCKS ((N_NODES + 255) / 256)   // 196

typedef __attribute__((ext_vector_type(8))) _Float16 halfx8;
typedef __attribute__((ext_vector_type(2))) _Float16 half2v;
typedef __attribute__((ext_vector_type(16))) float f32x16;

// ---------------------------------------------------------------------------
// CSR build
// ---------------------------------------------------------------------------
__global__ void count_kernel(const int* __restrict__ dst, int* __restrict__ cnt, int E) {
    int e = blockIdx.x * 256 + threadIdx.x;
    if (e < E) atomicAdd(&cnt[dst[e]], 1);
}

__global__ __launch_bounds__(256) void block_sum_kernel(const int* __restrict__ cnt,
                                                        int* __restrict__ bsum, int N) {
    int i = blockIdx.x * 256 + threadIdx.x;
    int c = (i < N) ? cnt[i] : 0;
#pragma unroll
    for (int off = 1; off < 64; off <<= 1) c += __shfl_xor(c, off);
    __shared__ int s[4];
    int wave = threadIdx.x >> 6;
    if ((threadIdx.x & 63) == 0) s[wave] = c;
    __syncthreads();
    if (threadIdx.x == 0) bsum[blockIdx.x] = s[0] + s[1] + s[2] + s[3];
}

__global__ __launch_bounds__(256) void scan_partials_kernel(const int* __restrict__ bsum,
                                                            int* __restrict__ boff,
                                                            int* __restrict__ csr_ptr) {
    __shared__ int s[256];
    int t = threadIdx.x;
    int v = (t < SCAN_BLOCKS) ? bsum[t] : 0;
    s[t] = v;
    __syncthreads();
    for (int off = 1; off < 256; off <<= 1) {
        int u = (t >= off) ? s[t - off] : 0;
        __syncthreads();
        s[t] += u;
        __syncthreads();
    }
    if (t < SCAN_BLOCKS) boff[t] = s[t] - v;
    if (t == 255) csr_ptr[N_NODES] = s[255];
}

__global__ __launch_bounds__(256) void scan_scatter_kernel(const int* __restrict__ cnt,
                                                           const int* __restrict__ boff,
                                                           int* __restrict__ csr_ptr,
                                                           int* __restrict__ cursor,
                                                           float* __restrict__ dinv, int N) {
    __shared__ int s[256];
    int t = threadIdx.x;
    int i = blockIdx.x * 256 + t;
    int c = (i < N) ? cnt[i] : 0;
    s[t] = c;
    __syncthreads();
    for (int off = 1; off < 256; off <<= 1) {
        int u = (t >= off) ? s[t - off] : 0;
        __syncthreads();
        s[t] += u;
        __syncthreads();
    }
    if (i < N) {
        int run = boff[blockIdx.x] + s[t] - c;
        csr_ptr[i] = run;
        cursor[i] = run;
        dinv[i] = 1.0f / sqrtf((float)(c + 1));
    }
}

// Scatter (src, eid) as one int2; dst filled separately (coalesced).
__global__ void fill_kernel(const int* __restrict__ src, const int* __restrict__ dst,
                            int* __restrict__ cursor, int2* __restrict__ ce_se, int E) {
    int e = blockIdx.x * 256 + threadIdx.x;
    if (e < E) {
        int pos = atomicAdd(&cursor[dst[e]], 1);
        ce_se[pos] = make_int2(src[e], e);
    }
}

__global__ void dst_fill_kernel(const int* __restrict__ ptr, int* __restrict__ ce_dst, int N) {
    int i = blockIdx.x * 256 + threadIdx.x;
    if (i < N) {
        int a = ptr[i], b = ptr[i + 1];
        for (int j = a; j < b; j++) ce_dst[j] = i;
    }
}

// ---------------------------------------------------------------------------
// x fp32 -> fp16
// ---------------------------------------------------------------------------
__global__ __launch_bounds__(256) void convert_x_kernel(const float* __restrict__ x,
                                                        _Float16* __restrict__ xh, int n4) {
    int i = blockIdx.x * 256 + threadIdx.x;
    if (i < n4) {
        float4 v = ((const float4*)x)[i];
        half2v a = {(_Float16)v.x, (_Float16)v.y};
        half2v b = {(_Float16)v.z, (_Float16)v.w};
        ((half2v*)xh)[i * 2] = a;
        ((half2v*)xh)[i * 2 + 1] = b;
    }
}

// ---------------------------------------------------------------------------
// Pack all weights into MFMA B-fragment order (fp16).
// For weight with K rows: packed[((cb*steps+s)*64+lane)*8+j] =
//   W[s*16 + (lane>>5)*8 + j][cb*32 + (lane&31)],  steps=K/16, cb=0..3.
// Segments: W_in(K=96)@0, W1@12288, W2@28672, Wm1top@45056, Wm1bot@61440.
// ---------------------------------------------------------------------------
__global__ __launch_bounds__(256) void pack_weights_kernel(const float* __restrict__ W_in,
                                                           const float* __restrict__ W1,
                                                           const float* __restrict__ W2,
                                                           const float* __restrict__ Wm1,
                                                           _Float16* __restrict__ packed) {
    int t = blockIdx.x * 256 + threadIdx.x;  // 0..77823
    const float* Wsrc;
    int K, u;
    if (t < 12288)      { Wsrc = W_in;            K = 96;  u = t; }
    else if (t < 28672) { Wsrc = W1;              K = 128; u = t - 12288; }
    else if (t < 45056) { Wsrc = W2;              K = 128; u = t - 28672; }
    else if (t < 61440) { Wsrc = Wm1;             K = 128; u = t - 45056; }
    else                { Wsrc = Wm1 + 128 * 128; K = 128; u = t - 61440; }
    if (t >= 77824) return;
    int steps = K >> 4;
    int cb = u / (steps * 512);
    int rem = u - cb * steps * 512;
    int s = rem >> 9;
    int lane = (rem >> 3) & 63;
    int j = rem & 7;
    int k = s * 16 + ((lane >> 5) << 3) + j;
    int n = (cb << 5) + (lane & 31);
    packed[t] = (_Float16)Wsrc[k * 128 + n];
}

// ---------------------------------------------------------------------------
// fp16 MFMA node GEMM: out[M][128] = A[M][K] @ W (packed) (+bias)(*rowscale)(relu)
// Block: 256 thr / 4 waves, tile M=64 x N=128. Wave: rows 32*(w&1),
// col tiles {64*(w>>1), +32}. v_mfma_f32_32x32x16_f16.
// ---------------------------------------------------------------------------
__global__ __launch_bounds__(256) void gemm_f16_kernel(const _Float16* __restrict__ A,
                                                       const _Float16* __restrict__ Wp,
                                                       const float* __restrict__ bias,
                                                       const float* __restrict__ rowscale,
                                                       _Float16* __restrict__ out,
                                                       int M, int K, int steps, int dorelu) {
    __shared__ _Float16 As[64 * 136];  // stride K+8 halves (16B-aligned, low conflict)
    int tid = threadIdx.x;
    int M0 = blockIdx.x * 64;
    int stride = K + 8;
    int CH = K >> 3;        // 8-half chunks per row
    int tot = 64 * CH;
    for (int i = tid; i < tot; i += 256) {
        int r = i / CH, c = i - r * CH;
        uint4 v = make_uint4(0, 0, 0, 0);
        int row = M0 + r;
        if (row < M) v = *(const uint4*)&A[(size_t)row * K + c * 8];
        *(uint4*)&As[r * stride + c * 8] = v;
    }
    __syncthreads();

    int wave = tid >> 6, lane = tid & 63;
    int rb = wave & 1;
    int cb0 = (wave >> 1) * 2;
    const halfx8* bp0 = (const halfx8*)Wp + (size_t)cb0 * steps * 64 + lane;
    const halfx8* bp1 = bp0 + (size_t)steps * 64;
    const _Float16* arow = &As[(rb * 32 + (lane & 31)) * stride + ((lane >> 5) << 3)];
    f32x16 acc0 = {}, acc1 = {};
    for (int s = 0; s < steps; s++) {
        halfx8 a = *(const halfx8*)&arow[s * 16];
        halfx8 b0 = bp0[s * 64];
        halfx8 b1 = bp1[s * 64];
        acc0 = __builtin_amdgcn_mfma_f32_32x32x16_f16(a, b0, acc0, 0, 0, 0);
        acc1 = __builtin_amdgcn_mfma_f32_32x32x16_f16(a, b1, acc1, 0, 0, 0);
    }

    int colA = cb0 * 32 + (lane & 31);
    int colB = colA + 32;
    float bA = bias ? bias[colA] : 0.f;
    float bB = bias ? bias[colB] : 0.f;
#pragma unroll
    for (int r = 0; r < 16; r++) {
        int rl = (r & 3) + 8 * (r >> 2) + 4 * (lane >> 5);  // C/D row map (m74/m101)
        int grow = M0 + rb * 32 + rl;
        if (grow < M) {
            float sc = rowscale ? rowscale[grow] : 1.f;
            float v0 = (acc0[r] + bA) * sc;
            float v1 = (acc1[r] + bB) * sc;
            if (dorelu) { v0 = fmaxf(v0, 0.f); v1 = fmaxf(v1, 0.f); }
            out[(size_t)grow * 128 + colA] = (_Float16)v0;
            out[(size_t)grow * 128 + colB] = (_Float16)v1;
        }
    }
}

// ---------------------------------------------------------------------------
// GCN aggregation, wave-per-node, fp16 rows, fp32 accumulate.
// ---------------------------------------------------------------------------
__global__ __launch_bounds__(256) void aggregate_kernel(const _Float16* __restrict__ y,
                                                        const float* __restrict__ dinv,
                                                        const int* __restrict__ ptr,
                                                        const int2* __restrict__ ce_se,
                                                        const float* __restrict__ bias,
                                                        _Float16* __restrict__ out) {
    int node = blockIdx.x * 4 + (threadIdx.x >> 6);
    int lane = threadIdx.x & 63;
    int c = lane * 2;
    float di = dinv[node];
    half2v self = ((const half2v*)&y[(size_t)node * 128])[lane];
    float a0 = (float)self.x, a1 = (float)self.y;
    float b0 = 0.f, b1 = 0.f, c0 = 0.f, c1 = 0.f, d0 = 0.f, d1 = 0.f;
    int s0 = ptr[node], s1 = ptr[node + 1];
    int j = s0;
    for (; j + 3 < s1; j += 4) {
        int n0 = ce_se[j].x, n1 = ce_se[j + 1].x, n2 = ce_se[j + 2].x, n3 = ce_se[j + 3].x;
        half2v v0 = ((const half2v*)&y[(size_t)n0 * 128])[lane];
        half2v v1 = ((const half2v*)&y[(size_t)n1 * 128])[lane];
        half2v v2 = ((const half2v*)&y[(size_t)n2 * 128])[lane];
        half2v v3 = ((const half2v*)&y[(size_t)n3 * 128])[lane];
        a0 += (float)v0.x; a1 += (float)v0.y;
        b0 += (float)v1.x; b1 += (float)v1.y;
        c0 += (float)v2.x; c1 += (float)v2.y;
        d0 += (float)v3.x; d1 += (float)v3.y;
    }
    for (; j < s1; j++) {
        int n = ce_se[j].x;
        half2v v = ((const half2v*)&y[(size_t)n * 128])[lane];
        a0 += (float)v.x; a1 += (float)v.y;
    }
    float2 bv = *(const float2*)&bias[c];
    float o0 = fmaxf(di * (a0 + b0 + c0 + d0) + bv.x, 0.f);
    float o1 = fmaxf(di * (a1 + b1 + c1 + d1) + bv.y, 0.f);
    half2v ov = {(_Float16)o0, (_Float16)o1};
    ((half2v*)&out[(size_t)node * 128])[lane] = ov;
}

// ---------------------------------------------------------------------------
// Edge MLP via U/V decomposition (fp16 tables, CSR order; V gathers L1-hot).
// ---------------------------------------------------------------------------
__global__ __launch_bounds__(256) void edge_mlp_kernel(const _Float16* __restrict__ Ub,
                                                       const _Float16* __restrict__ Vb,
                                                       const int2* __restrict__ ce_se,
                                                       const int* __restrict__ ce_dst,
                                                       const float* __restrict__ Wm2,
                                                       const float* __restrict__ bm2,
                                                       float* __restrict__ out) {
    __shared__ int ssrc[16], sdst[16], seid[16];
    int tid = threadIdx.x;
    int e0 = blockIdx.x * 16;
    if (tid < 16) {
        int2 se = ce_se[e0 + tid];
        ssrc[tid] = se.x;
        seid[tid] = se.y;
    } else if (tid < 32) {
        sdst[tid - 16] = ce_dst[e0 + tid - 16];
    }
    __syncthreads();
    int g = tid >> 4;
    int l = tid & 15;
    halfx8 u = *(const halfx8*)&Ub[(size_t)ssrc[g] * 128 + l * 8];
    halfx8 v = *(const halfx8*)&Vb[(size_t)sdst[g] * 128 + l * 8];
    float4 w0 = *(const float4*)&Wm2[l * 8];
    float4 w1 = *(const float4*)&Wm2[l * 8 + 4];
    float wm[8] = {w0.x, w0.y, w0.z, w0.w, w1.x, w1.y, w1.z, w1.w};
    float p = 0.f;
#pragma unroll
    for (int t = 0; t < 8; t++) {
        float h = fmaxf((float)u[t] + (float)v[t], 0.f);
        p = fmaf(h, wm[t], p);
    }
    p += __shfl_xor(p, 1);
    p += __shfl_xor(p, 2);
    p += __shfl_xor(p, 4);
    p += __shfl_xor(p, 8);
    if (l == 0) out[seid[g]] = p + bm2[0];
}

// ---------------------------------------------------------------------------
extern "C" void kernel_launch(void* const* d_in, const int* in_sizes, int n_in,
                              void* d_out, int out_size, void* d_ws, size_t ws_size,
                              hipStream_t stream) {
    const float* x    = (const float*)d_in[0];
    const int* eidx   = (const int*)d_in[1];
    const float* W_in = (const float*)d_in[2];
    const float* b_in = (const float*)d_in[3];
    const float* W1   = (const float*)d_in[4];
    const float* b1   = (const float*)d_in[5];
    const float* W2   = (const float*)d_in[6];
    const float* b2   = (const float*)d_in[7];
    const float* Wm1  = (const float*)d_in[8];
    const float* bm1  = (const float*)d_in[9];
    const float* Wm2  = (const float*)d_in[10];
    const float* bm2  = (const float*)d_in[11];
    float* out = (float*)d_out;
    const int* src = eidx;
    const int* dst = eidx + N_EDGES;

    char* w = (char*)d_ws;
    size_t off = 0;
    auto alloc = [&](size_t bytes) -> char* {
        char* p = w + off;
        off = (off + bytes + 255) & ~(size_t)255;
        return p;
    };
    int* cnt      = (int*)alloc((size_t)N_NODES * 4);
    int* csr_ptr  = (int*)alloc((size_t)(N_NODES + 1) * 4);
    int* cursor   = (int*)alloc((size_t)N_NODES * 4);
    float* dinv   = (float*)alloc((size_t)N_NODES * 4);
    int* bsum     = (int*)alloc((size_t)SCAN_BLOCKS * 4);
    int* boff     = (int*)alloc((size_t)SCAN_BLOCKS * 4);
    int2* ce_se   = (int2*)alloc((size_t)N_EDGES * 8);
    int* ce_dst   = (int*)alloc((size_t)N_EDGES * 4);
    _Float16* xh  = (_Float16*)alloc((size_t)N_NODES * D_IN * 2);
    _Float16* Wp  = (_Float16*)alloc((size_t)77824 * 2);
    _Float16* hbuf = (_Float16*)alloc((size_t)N_NODES * HID * 2);
    _Float16* ybuf = (_Float16*)alloc((size_t)N_NODES * HID * 2);
    _Float16* Ub  = (_Float16*)alloc((size_t)N_NODES * HID * 2);
    _Float16* Vb  = (_Float16*)alloc((size_t)N_NODES * HID * 2);

    const _Float16* WpIn  = Wp;              // K=96, steps 6
    const _Float16* Wp1   = Wp + 12288;      // K=128, steps 8
    const _Float16* Wp2   = Wp + 28672;
    const _Float16* WpM1a = Wp + 45056;
    const _Float16* WpM1b = Wp + 61440;

    hipMemsetAsync(cnt, 0, (size_t)N_NODES * 4, stream);
    count_kernel<<<(N_EDGES + 255) / 256, 256, 0, stream>>>(dst, cnt, N_EDGES);
    block_sum_kernel<<<SCAN_BLOCKS, 256, 0, stream>>>(cnt, bsum, N_NODES);
    scan_partials_kernel<<<1, 256, 0, stream>>>(bsum, boff, csr_ptr);
    scan_scatter_kernel<<<SCAN_BLOCKS, 256, 0, stream>>>(cnt, boff, csr_ptr, cursor,
                                                         dinv, N_NODES);
    fill_kernel<<<(N_EDGES + 255) / 256, 256, 0, stream>>>(src, dst, cursor, ce_se, N_EDGES);
    dst_fill_kernel<<<SCAN_BLOCKS, 256, 0, stream>>>(csr_ptr, ce_dst, N_NODES);
    convert_x_kernel<<<(N_NODES * D_IN / 4 + 255) / 256, 256, 0, stream>>>(
        x, xh, N_NODES * D_IN / 4);
    pack_weights_kernel<<<(77824 + 255) / 256, 256, 0, stream>>>(W_in, W1, W2, Wm1, Wp);

    int gblocks = (N_NODES + 63) / 64;
    // h0 = relu(x @ W_in + b_in)                    -> hbuf
    gemm_f16_kernel<<<gblocks, 256, 0, stream>>>(xh, WpIn, b_in, nullptr, hbuf,
                                                 N_NODES, D_IN, 6, 1);
    // y1 = (h0 @ W1) * dinv[row]                    -> ybuf
    gemm_f16_kernel<<<gblocks, 256, 0, stream>>>(hbuf, Wp1, nullptr, dinv, ybuf,
                                                 N_NODES, HID, 8, 0);
    // h1 = relu(dinv*(y1_self + sum y1[src]) + b1)  -> hbuf
    aggregate_kernel<<<N_NODES / 4, 256, 0, stream>>>(ybuf, dinv, csr_ptr, ce_se, b1, hbuf);
    // y2 = (h1 @ W2) * dinv[row]                    -> ybuf
    gemm_f16_kernel<<<gblocks, 256, 0, stream>>>(hbuf, Wp2, nullptr, dinv, ybuf,
                                                 N_NODES, HID, 8, 0);
    // h2 = relu(dinv*(y2_self + sum y2[src]) + b2)  -> hbuf
    aggregate_kernel<<<N_NODES / 4, 256, 0, stream>>>(ybuf, dinv, csr_ptr, ce_se, b2, hbuf);
    // U = h2 @ Wm1[:128] + bm1                      -> Ub
    gemm_f16_kernel<<<gblocks, 256, 0, stream>>>(hbuf, WpM1a, bm1, nullptr, Ub,
                                                 N_NODES, HID, 8, 0);
    // V = h2 @ Wm1[128:]                            -> Vb
    gemm_f16_kernel<<<gblocks, 256, 0, stream>>>(hbuf, WpM1b, nullptr, nullptr, Vb,
                                                 N_NODES, HID, 8, 0);
    // logits (CSR order, scatter by original edge id)
    edge_mlp_kernel<<<N_EDGES / 16, 256, 0, stream>>>(Ub, Vb, ce_se, ce_dst, Wm2, bm2, out);
}

// Round 6
// 296.986 us; speedup vs baseline: 4.1155x; 1.2629x over previous
//
#include <hip/hip_runtime.h>

#define N_NODES 50000
#define N_EDGES 800000
#define D_IN 96
#define HID 128
#define NB 391              // buckets of 128 nodes: (50000+127)/128
#define BCAP 3072           // per-bucket edge cap (avg 2046, sigma ~45)

typedef __attribute__((ext_vector_type(8))) _Float16 halfx8;
typedef __attribute__((ext_vector_type(2))) _Float16 half2v;
typedef __attribute__((ext_vector_type(16))) float f32x16;

// ---------------------------------------------------------------------------
// CSR build via LDS-binned counting sort.
// pack = src(16b)<<27 | dstloc(7b)<<20 | eid(20b)
// ---------------------------------------------------------------------------

// Pass A: bucket histogram. 196 blocks x 256 thr x 16 edges.
__global__ __launch_bounds__(256) void bucket_hist_kernel(const int* __restrict__ dst,
                                                          int* __restrict__ bhist) {
    __shared__ int lh[NB];
    int t = threadIdx.x;
    for (int i = t; i < NB; i += 256) lh[i] = 0;
    __syncthreads();
    int base = blockIdx.x * 4096;
#pragma unroll
    for (int i = 0; i < 16; i++) {
        int e = base + i * 256 + t;
        if (e < N_EDGES) atomicAdd(&lh[dst[e] >> 7], 1);
    }
    __syncthreads();
    for (int i = t; i < NB; i += 256) atomicAdd(&bhist[i], lh[i]);
}

// Pass B scan: exclusive scan of 391 bucket counts -> boff[392], bcursor.
__global__ __launch_bounds__(512) void scan_buckets_kernel(const int* __restrict__ bhist,
                                                           int* __restrict__ boff,
                                                           int* __restrict__ bcursor) {
    __shared__ int s[512];
    int t = threadIdx.x;
    int v = (t < NB) ? bhist[t] : 0;
    s[t] = v;
    __syncthreads();
    for (int off = 1; off < 512; off <<= 1) {
        int u = (t >= off) ? s[t - off] : 0;
        __syncthreads();
        s[t] += u;
        __syncthreads();
    }
    if (t < NB) {
        int ex = s[t] - v;
        boff[t] = ex;
        bcursor[t] = ex;
    }
    if (t == NB - 1) boff[NB] = s[t];
}

// Pass C: bin edges into bucket regions (packed ulong), block-aggregated runs.
// 98 blocks x 512 thr x 16 edges.
__global__ __launch_bounds__(512) void bin_kernel(const int* __restrict__ src,
                                                  const int* __restrict__ dst,
                                                  int* __restrict__ bcursor,
                                                  unsigned long long* __restrict__ binned) {
    __shared__ int lh[NB];
    __shared__ int gbs[NB];
    int t = threadIdx.x;
    for (int i = t; i < NB; i += 512) lh[i] = 0;
    __syncthreads();
    int base = blockIdx.x * 8192;
    unsigned long long pk[16];
    int bb[16], rk[16];
#pragma unroll
    for (int i = 0; i < 16; i++) {
        int e = base + i * 512 + t;
        bb[i] = -1;
        if (e < N_EDGES) {
            int s = src[e], d = dst[e];
            int b = d >> 7;
            bb[i] = b;
            pk[i] = ((unsigned long long)s << 27) |
                    ((unsigned long long)(d & 127) << 20) | (unsigned long long)e;
            rk[i] = atomicAdd(&lh[b], 1);
        }
    }
    __syncthreads();
    for (int i = t; i < NB; i += 512) gbs[i] = atomicAdd(&bcursor[i], lh[i]);
    __syncthreads();
#pragma unroll
    for (int i = 0; i < 16; i++) {
        if (bb[i] >= 0) binned[gbs[bb[i]] + rk[i]] = pk[i];
    }
}

// Pass D: per-bucket LDS sort by exact dst; write ce_se/ce_dst/csr_ptr/dinv coalesced.
__global__ __launch_bounds__(256) void bucket_sort_kernel(const unsigned long long* __restrict__ binned,
                                                          const int* __restrict__ boff,
                                                          int2* __restrict__ ce_se,
                                                          int* __restrict__ ce_dst,
                                                          int* __restrict__ csr_ptr,
                                                          float* __restrict__ dinv) {
    __shared__ unsigned long long ed[BCAP];
    __shared__ int2 sorted[BCAP];
    __shared__ int cntA[128], sc[128];
    int b = blockIdx.x;
    int t = threadIdx.x;
    int base = boff[b];
    int k = boff[b + 1] - base;
    if (k > BCAP) k = BCAP;  // safety clamp (never hit on this graph)
    if (t < 128) { cntA[t] = 0; }
    __syncthreads();
    // load + rank
    int rk[12], li[12];
    int nmine = 0;
    for (int i = t; i < k; i += 256) {
        unsigned long long p = binned[base + i];
        ed[i] = p;
        int d = (int)((p >> 20) & 127);
        rk[nmine] = atomicAdd(&cntA[d], 1);
        li[nmine] = i;
        nmine++;
    }
    __syncthreads();
    // inclusive scan of counts (128 entries)
    if (t < 128) sc[t] = cntA[t];
    __syncthreads();
    for (int off = 1; off < 128; off <<= 1) {
        int u = 0;
        if (t < 128 && t >= off) u = sc[t - off];
        __syncthreads();
        if (t < 128) sc[t] += u;
        __syncthreads();
    }
    // place into sorted order in LDS
    for (int m = 0; m < nmine; m++) {
        unsigned long long p = ed[li[m]];
        int d = (int)((p >> 20) & 127);
        int pos = sc[d] - cntA[d] + rk[m];
        int srcn = (int)(p >> 27);
        int eid = (int)(p & 0xFFFFF);
        sorted[pos] = make_int2(srcn | (d << 16), eid);
    }
    __syncthreads();
    // coalesced writes
    for (int i = t; i < k; i += 256) {
        int2 se = sorted[i];
        ce_se[base + i] = make_int2(se.x & 0xFFFF, se.y);
        ce_dst[base + i] = (b << 7) + (se.x >> 16);
    }
    if (t < 128) {
        int node = (b << 7) + t;
        if (node < N_NODES) {
            csr_ptr[node] = base + sc[t] - cntA[t];
            dinv[node] = 1.0f / sqrtf((float)(cntA[t] + 1));
        }
    }
    if (b == NB - 1 && t == 0) csr_ptr[N_NODES] = boff[NB];
}

// ---------------------------------------------------------------------------
// x fp32 -> fp16
// ---------------------------------------------------------------------------
__global__ __launch_bounds__(256) void convert_x_kernel(const float* __restrict__ x,
                                                        _Float16* __restrict__ xh, int n4) {
    int i = blockIdx.x * 256 + threadIdx.x;
    if (i < n4) {
        float4 v = ((const float4*)x)[i];
        half2v a = {(_Float16)v.x, (_Float16)v.y};
        half2v b = {(_Float16)v.z, (_Float16)v.w};
        ((half2v*)xh)[i * 2] = a;
        ((half2v*)xh)[i * 2 + 1] = b;
    }
}

// ---------------------------------------------------------------------------
// Pack weights into MFMA B-fragment order (fp16).
// ---------------------------------------------------------------------------
__global__ __launch_bounds__(256) void pack_weights_kernel(const float* __restrict__ W_in,
                                                           const float* __restrict__ W1,
                                                           const float* __restrict__ W2,
                                                           const float* __restrict__ Wm1,
                                                           _Float16* __restrict__ packed) {
    int t = blockIdx.x * 256 + threadIdx.x;  // 0..77823
    const float* Wsrc;
    int K, u;
    if (t < 12288)      { Wsrc = W_in;            K = 96;  u = t; }
    else if (t < 28672) { Wsrc = W1;              K = 128; u = t - 12288; }
    else if (t < 45056) { Wsrc = W2;              K = 128; u = t - 28672; }
    else if (t < 61440) { Wsrc = Wm1;             K = 128; u = t - 45056; }
    else                { Wsrc = Wm1 + 128 * 128; K = 128; u = t - 61440; }
    if (t >= 77824) return;
    int steps = K >> 4;
    int cb = u / (steps * 512);
    int rem = u - cb * steps * 512;
    int s = rem >> 9;
    int lane = (rem >> 3) & 63;
    int j = rem & 7;
    int k = s * 16 + ((lane >> 5) << 3) + j;
    int n = (cb << 5) + (lane & 31);
    packed[t] = (_Float16)Wsrc[k * 128 + n];
}

// ---------------------------------------------------------------------------
// fp16 MFMA node GEMM (single output)
// ---------------------------------------------------------------------------
__global__ __launch_bounds__(256) void gemm_f16_kernel(const _Float16* __restrict__ A,
                                                       const _Float16* __restrict__ Wp,
                                                       const float* __restrict__ bias,
                                                       const float* __restrict__ rowscale,
                                                       _Float16* __restrict__ out,
                                                       int M, int K, int steps, int dorelu) {
    __shared__ _Float16 As[64 * 136];
    int tid = threadIdx.x;
    int M0 = blockIdx.x * 64;
    int stride = K + 8;
    int CH = K >> 3;
    int tot = 64 * CH;
    for (int i = tid; i < tot; i += 256) {
        int r = i / CH, c = i - r * CH;
        uint4 v = make_uint4(0, 0, 0, 0);
        int row = M0 + r;
        if (row < M) v = *(const uint4*)&A[(size_t)row * K + c * 8];
        *(uint4*)&As[r * stride + c * 8] = v;
    }
    __syncthreads();

    int wave = tid >> 6, lane = tid & 63;
    int rb = wave & 1;
    int cb0 = (wave >> 1) * 2;
    const halfx8* bp0 = (const halfx8*)Wp + (size_t)cb0 * steps * 64 + lane;
    const halfx8* bp1 = bp0 + (size_t)steps * 64;
    const _Float16* arow = &As[(rb * 32 + (lane & 31)) * stride + ((lane >> 5) << 3)];
    f32x16 acc0 = {}, acc1 = {};
    for (int s = 0; s < steps; s++) {
        halfx8 a = *(const halfx8*)&arow[s * 16];
        halfx8 b0 = bp0[s * 64];
        halfx8 b1 = bp1[s * 64];
        acc0 = __builtin_amdgcn_mfma_f32_32x32x16_f16(a, b0, acc0, 0, 0, 0);
        acc1 = __builtin_amdgcn_mfma_f32_32x32x16_f16(a, b1, acc1, 0, 0, 0);
    }

    int colA = cb0 * 32 + (lane & 31);
    int colB = colA + 32;
    float bA = bias ? bias[colA] : 0.f;
    float bB = bias ? bias[colB] : 0.f;
#pragma unroll
    for (int r = 0; r < 16; r++) {
        int rl = (r & 3) + 8 * (r >> 2) + 4 * (lane >> 5);
        int grow = M0 + rb * 32 + rl;
        if (grow < M) {
            float sc = rowscale ? rowscale[grow] : 1.f;
            float v0 = (acc0[r] + bA) * sc;
            float v1 = (acc1[r] + bB) * sc;
            if (dorelu) { v0 = fmaxf(v0, 0.f); v1 = fmaxf(v1, 0.f); }
            out[(size_t)grow * 128 + colA] = (_Float16)v0;
            out[(size_t)grow * 128 + colB] = (_Float16)v1;
        }
    }
}

// Dual-output GEMM: U = A@WpU + bm1, V = A@WpV (A staged once).
__global__ __launch_bounds__(256) void gemm_uv_kernel(const _Float16* __restrict__ A,
                                                      const _Float16* __restrict__ WpU,
                                                      const _Float16* __restrict__ WpV,
                                                      const float* __restrict__ bm1,
                                                      _Float16* __restrict__ U,
                                                      _Float16* __restrict__ V,
                                                      int M) {
    const int K = 128, steps = 8;
    __shared__ _Float16 As[64 * 136];
    int tid = threadIdx.x;
    int M0 = blockIdx.x * 64;
    int stride = K + 8;
    for (int i = tid; i < 64 * 16; i += 256) {
        int r = i >> 4, c = i & 15;
        uint4 v = make_uint4(0, 0, 0, 0);
        int row = M0 + r;
        if (row < M) v = *(const uint4*)&A[(size_t)row * K + c * 8];
        *(uint4*)&As[r * stride + c * 8] = v;
    }
    __syncthreads();

    int wave = tid >> 6, lane = tid & 63;
    int rb = wave & 1;
    int cb0 = (wave >> 1) * 2;
    const halfx8* bu0 = (const halfx8*)WpU + (size_t)cb0 * steps * 64 + lane;
    const halfx8* bu1 = bu0 + (size_t)steps * 64;
    const halfx8* bv0 = (const halfx8*)WpV + (size_t)cb0 * steps * 64 + lane;
    const halfx8* bv1 = bv0 + (size_t)steps * 64;
    const _Float16* arow = &As[(rb * 32 + (lane & 31)) * stride + ((lane >> 5) << 3)];
    f32x16 au0 = {}, au1 = {}, av0 = {}, av1 = {};
    for (int s = 0; s < steps; s++) {
        halfx8 a = *(const halfx8*)&arow[s * 16];
        au0 = __builtin_amdgcn_mfma_f32_32x32x16_f16(a, bu0[s * 64], au0, 0, 0, 0);
        au1 = __builtin_amdgcn_mfma_f32_32x32x16_f16(a, bu1[s * 64], au1, 0, 0, 0);
        av0 = __builtin_amdgcn_mfma_f32_32x32x16_f16(a, bv0[s * 64], av0, 0, 0, 0);
        av1 = __builtin_amdgcn_mfma_f32_32x32x16_f16(a, bv1[s * 64], av1, 0, 0, 0);
    }

    int colA = cb0 * 32 + (lane & 31);
    int colB = colA + 32;
    float bA = bm1[colA], bB = bm1[colB];
#pragma unroll
    for (int r = 0; r < 16; r++) {
        int rl = (r & 3) + 8 * (r >> 2) + 4 * (lane >> 5);
        int grow = M0 + rb * 32 + rl;
        if (grow < M) {
            U[(size_t)grow * 128 + colA] = (_Float16)(au0[r] + bA);
            U[(size_t)grow * 128 + colB] = (_Float16)(au1[r] + bB);
            V[(size_t)grow * 128 + colA] = (_Float16)av0[r];
            V[(size_t)grow * 128 + colB] = (_Float16)av1[r];
        }
    }
}

// ---------------------------------------------------------------------------
// GCN aggregation, wave-per-node, fp16 rows, fp32 accumulate, 8-way unroll.
// ---------------------------------------------------------------------------
__global__ __launch_bounds__(256) void aggregate_kernel(const _Float16* __restrict__ y,
                                                        const float* __restrict__ dinv,
                                                        const int* __restrict__ ptr,
                                                        const int2* __restrict__ ce_se,
                                                        const float* __restrict__ bias,
                                                        _Float16* __restrict__ out) {
    int node = blockIdx.x * 4 + (threadIdx.x >> 6);
    int lane = threadIdx.x & 63;
    int c = lane * 2;
    float di = dinv[node];
    half2v self = ((const half2v*)&y[(size_t)node * 128])[lane];
    float a0 = (float)self.x, a1 = (float)self.y;
    float b0 = 0.f, b1 = 0.f, c0 = 0.f, c1 = 0.f, d0 = 0.f, d1 = 0.f;
    int s0 = ptr[node], s1 = ptr[node + 1];
    int j = s0;
    for (; j + 7 < s1; j += 8) {
        int n0 = ce_se[j].x, n1 = ce_se[j + 1].x, n2 = ce_se[j + 2].x, n3 = ce_se[j + 3].x;
        int n4 = ce_se[j + 4].x, n5 = ce_se[j + 5].x, n6 = ce_se[j + 6].x, n7 = ce_se[j + 7].x;
        half2v v0 = ((const half2v*)&y[(size_t)n0 * 128])[lane];
        half2v v1 = ((const half2v*)&y[(size_t)n1 * 128])[lane];
        half2v v2 = ((const half2v*)&y[(size_t)n2 * 128])[lane];
        half2v v3 = ((const half2v*)&y[(size_t)n3 * 128])[lane];
        half2v v4 = ((const half2v*)&y[(size_t)n4 * 128])[lane];
        half2v v5 = ((const half2v*)&y[(size_t)n5 * 128])[lane];
        half2v v6 = ((const half2v*)&y[(size_t)n6 * 128])[lane];
        half2v v7 = ((const half2v*)&y[(size_t)n7 * 128])[lane];
        a0 += (float)v0.x + (float)v4.x; a1 += (float)v0.y + (float)v4.y;
        b0 += (float)v1.x + (float)v5.x; b1 += (float)v1.y + (float)v5.y;
        c0 += (float)v2.x + (float)v6.x; c1 += (float)v2.y + (float)v6.y;
        d0 += (float)v3.x + (float)v7.x; d1 += (float)v3.y + (float)v7.y;
    }
    for (; j < s1; j++) {
        int n = ce_se[j].x;
        half2v v = ((const half2v*)&y[(size_t)n * 128])[lane];
        a0 += (float)v.x; a1 += (float)v.y;
    }
    float2 bv = *(const float2*)&bias[c];
    float o0 = fmaxf(di * (a0 + b0 + c0 + d0) + bv.x, 0.f);
    float o1 = fmaxf(di * (a1 + b1 + c1 + d1) + bv.y, 0.f);
    half2v ov = {(_Float16)o0, (_Float16)o1};
    ((half2v*)&out[(size_t)node * 128])[lane] = ov;
}

// ---------------------------------------------------------------------------
// Edge MLP via U/V decomposition; 32 edges/block (2 per 16-lane group).
// ---------------------------------------------------------------------------
__global__ __launch_bounds__(256) void edge_mlp_kernel(const _Float16* __restrict__ Ub,
                                                       const _Float16* __restrict__ Vb,
                                                       const int2* __restrict__ ce_se,
                                                       const int* __restrict__ ce_dst,
                                                       const float* __restrict__ Wm2,
                                                       const float* __restrict__ bm2,
                                                       float* __restrict__ out) {
    __shared__ int ssrc[32], sdst[32], seid[32];
    int tid = threadIdx.x;
    int e0 = blockIdx.x * 32;
    if (tid < 32) {
        int2 se = ce_se[e0 + tid];
        ssrc[tid] = se.x;
        seid[tid] = se.y;
    } else if (tid < 64) {
        sdst[tid - 32] = ce_dst[e0 + tid - 32];
    }
    __syncthreads();
    int g = tid >> 4;
    int l = tid & 15;
    int g2 = g + 16;
    halfx8 u0 = *(const halfx8*)&Ub[(size_t)ssrc[g] * 128 + l * 8];
    halfx8 v0 = *(const halfx8*)&Vb[(size_t)sdst[g] * 128 + l * 8];
    halfx8 u1 = *(const halfx8*)&Ub[(size_t)ssrc[g2] * 128 + l * 8];
    halfx8 v1 = *(const halfx8*)&Vb[(size_t)sdst[g2] * 128 + l * 8];
    float4 w0 = *(const float4*)&Wm2[l * 8];
    float4 w1 = *(const float4*)&Wm2[l * 8 + 4];
    float wm[8] = {w0.x, w0.y, w0.z, w0.w, w1.x, w1.y, w1.z, w1.w};
    float p0 = 0.f, p1 = 0.f;
#pragma unroll
    for (int t = 0; t < 8; t++) {
        p0 = fmaf(fmaxf((float)u0[t] + (float)v0[t], 0.f), wm[t], p0);
        p1 = fmaf(fmaxf((float)u1[t] + (float)v1[t], 0.f), wm[t], p1);
    }
    p0 += __shfl_xor(p0, 1); p1 += __shfl_xor(p1, 1);
    p0 += __shfl_xor(p0, 2); p1 += __shfl_xor(p1, 2);
    p0 += __shfl_xor(p0, 4); p1 += __shfl_xor(p1, 4);
    p0 += __shfl_xor(p0, 8); p1 += __shfl_xor(p1, 8);
    if (l == 0) {
        float bb = bm2[0];
        out[seid[g]] = p0 + bb;
        out[seid[g2]] = p1 + bb;
    }
}

// ---------------------------------------------------------------------------
extern "C" void kernel_launch(void* const* d_in, const int* in_sizes, int n_in,
                              void* d_out, int out_size, void* d_ws, size_t ws_size,
                              hipStream_t stream) {
    const float* x    = (const float*)d_in[0];
    const int* eidx   = (const int*)d_in[1];
    const float* W_in = (const float*)d_in[2];
    const float* b_in = (const float*)d_in[3];
    const float* W1   = (const float*)d_in[4];
    const float* b1   = (const float*)d_in[5];
    const float* W2   = (const float*)d_in[6];
    const float* b2   = (const float*)d_in[7];
    const float* Wm1  = (const float*)d_in[8];
    const float* bm1  = (const float*)d_in[9];
    const float* Wm2  = (const float*)d_in[10];
    const float* bm2  = (const float*)d_in[11];
    float* out = (float*)d_out;
    const int* src = eidx;
    const int* dst = eidx + N_EDGES;

    char* w = (char*)d_ws;
    size_t off = 0;
    auto alloc = [&](size_t bytes) -> char* {
        char* p = w + off;
        off = (off + bytes + 255) & ~(size_t)255;
        return p;
    };
    int* bhist    = (int*)alloc((size_t)NB * 4);
    int* boff     = (int*)alloc((size_t)(NB + 1) * 4);
    int* bcursor  = (int*)alloc((size_t)NB * 4);
    int* csr_ptr  = (int*)alloc((size_t)(N_NODES + 1) * 4);
    float* dinv   = (float*)alloc((size_t)N_NODES * 4);
    unsigned long long* binned = (unsigned long long*)alloc((size_t)N_EDGES * 8);
    int2* ce_se   = (int2*)alloc((size_t)N_EDGES * 8);
    int* ce_dst   = (int*)alloc((size_t)N_EDGES * 4);
    _Float16* xh  = (_Float16*)alloc((size_t)N_NODES * D_IN * 2);
    _Float16* Wp  = (_Float16*)alloc((size_t)77824 * 2);
    _Float16* hbuf = (_Float16*)alloc((size_t)N_NODES * HID * 2);
    _Float16* ybuf = (_Float16*)alloc((size_t)N_NODES * HID * 2);
    _Float16* Ub  = (_Float16*)alloc((size_t)N_NODES * HID * 2);
    _Float16* Vb  = (_Float16*)alloc((size_t)N_NODES * HID * 2);

    const _Float16* WpIn  = Wp;              // K=96, steps 6
    const _Float16* Wp1   = Wp + 12288;      // K=128, steps 8
    const _Float16* Wp2   = Wp + 28672;
    const _Float16* WpM1a = Wp + 45056;
    const _Float16* WpM1b = Wp + 61440;

    // CSR build (counting sort)
    hipMemsetAsync(bhist, 0, (size_t)NB * 4, stream);
    bucket_hist_kernel<<<196, 256, 0, stream>>>(dst, bhist);
    scan_buckets_kernel<<<1, 512, 0, stream>>>(bhist, boff, bcursor);
    bin_kernel<<<98, 512, 0, stream>>>(src, dst, bcursor, binned);
    bucket_sort_kernel<<<NB, 256, 0, stream>>>(binned, boff, ce_se, ce_dst, csr_ptr, dinv);

    convert_x_kernel<<<(N_NODES * D_IN / 4 + 255) / 256, 256, 0, stream>>>(
        x, xh, N_NODES * D_IN / 4);
    pack_weights_kernel<<<(77824 + 255) / 256, 256, 0, stream>>>(W_in, W1, W2, Wm1, Wp);

    int gblocks = (N_NODES + 63) / 64;
    // h0 = relu(x @ W_in + b_in)                    -> hbuf
    gemm_f16_kernel<<<gblocks, 256, 0, stream>>>(xh, WpIn, b_in, nullptr, hbuf,
                                                 N_NODES, D_IN, 6, 1);
    // y1 = (h0 @ W1) * dinv[row]                    -> ybuf
    gemm_f16_kernel<<<gblocks, 256, 0, stream>>>(hbuf, Wp1, nullptr, dinv, ybuf,
                                                 N_NODES, HID, 8, 0);
    // h1 = relu(dinv*(y1_self + sum y1[src]) + b1)  -> hbuf
    aggregate_kernel<<<N_NODES / 4, 256, 0, stream>>>(ybuf, dinv, csr_ptr, ce_se, b1, hbuf);
    // y2 = (h1 @ W2) * dinv[row]                    -> ybuf
    gemm_f16_kernel<<<gblocks, 256, 0, stream>>>(hbuf, Wp2, nullptr, dinv, ybuf,
                                                 N_NODES, HID, 8, 0);
    // h2 = relu(dinv*(y2_self + sum y2[src]) + b2)  -> hbuf
    aggregate_kernel<<<N_NODES / 4, 256, 0, stream>>>(ybuf, dinv, csr_ptr, ce_se, b2, hbuf);
    // U = h2@Wm1[:128]+bm1, V = h2@Wm1[128:]        -> Ub, Vb (one dispatch)
    gemm_uv_kernel<<<gblocks, 256, 0, stream>>>(hbuf, WpM1a, WpM1b, bm1, Ub, Vb, N_NODES);
    // logits (CSR order, scatter by original edge id)
    edge_mlp_kernel<<<N_EDGES / 32, 256, 0, stream>>>(Ub, Vb, ce_se, ce_dst, Wm2, bm2, out);
}